// Round 2
// baseline (1465.693 us; speedup 1.0000x reference)
//
#include <hip/hip_runtime.h>
#include <hip/hip_bf16.h>

typedef __hip_bfloat16 bf16;

// ---------------------------------------------------------------------------
// 3-layer GAT forward, dtype-adaptive (handles float inputs arriving as either
// f32 or bf16, edge_index as int32 or int64). Flags computed on-device:
//   flags[0]=1 if any NaN/Inf bit-pattern among ushort halves of x  (=> f32)
//   flags[1]=1 if any odd 32-bit word of edge_index probe range nonzero (=> i32)
//   flags[2]=1 if any even-index ushort of x nonzero (bf16 values / f32 lo-half)
// isf32 = flags[0] || !flags[2].  e64 = !flags[1].
// ---------------------------------------------------------------------------

static __device__ __forceinline__ float loadf(const void* p, size_t i, int isf32) {
    return isf32 ? ((const float*)p)[i] : __bfloat162float(((const bf16*)p)[i]);
}
static __device__ __forceinline__ int get_isf32(const int* flags) {
    return (flags[0] | (flags[2] == 0)) ? 1 : 0;
}

__global__ void k_zero_i(int* __restrict__ p, int n) {
    int i = blockIdx.x * blockDim.x + threadIdx.x;
    if (i < n) p[i] = 0;
}

__global__ void k_detect_x(const unsigned short* __restrict__ u, int* __restrict__ flags, int n) {
    int i = blockIdx.x * blockDim.x + threadIdx.x;
    if (i >= n) return;
    unsigned short v = u[i];
    if ((v & 0x7F80u) == 0x7F80u) atomicOr(&flags[0], 1);
    if (((i & 1) == 0) && v != 0) atomicOr(&flags[2], 1);
}

__global__ void k_detect_e(const int* __restrict__ w, int* __restrict__ flags, int n2) {
    int i = blockIdx.x * blockDim.x + threadIdx.x;
    if (i >= n2) return;
    if ((i & 1) && w[i] != 0) atomicOr(&flags[1], 1);
}

__global__ void k_norm_x(const void* __restrict__ x, const int* __restrict__ flags,
                         float* __restrict__ fx, int n) {
    int i = blockIdx.x * blockDim.x + threadIdx.x;
    if (i >= n) return;
    fx[i] = loadf(x, i, get_isf32(flags));
}

// normalize edges to int32 src/dst arrays
__global__ void k_norm_e(const int* __restrict__ w, const int* __restrict__ flags,
                         int* __restrict__ s, int* __restrict__ d, int E) {
    int e = blockIdx.x * blockDim.x + threadIdx.x;
    if (e >= E) return;
    if (flags[1] == 0) {  // int64: row0 = words [0,2E), row1 = words [2E,4E)
        s[e] = w[2 * (size_t)e];
        d[e] = w[2 * (size_t)E + 2 * (size_t)e];
    } else {              // int32
        s[e] = w[e];
        d[e] = w[(size_t)E + e];
    }
}

__global__ void k_copy_i(const int* __restrict__ a, int* __restrict__ b, int n) {
    int i = blockIdx.x * blockDim.x + threadIdx.x;
    if (i < n) b[i] = a[i];
}

__global__ void k_count(const int* __restrict__ edst, int* __restrict__ cnt, int E, int N) {
    int e = blockIdx.x * blockDim.x + threadIdx.x;
    if (e >= E + N) return;
    int d = (e < E) ? edst[e] : (e - E);
    atomicAdd(&cnt[d], 1);
}

// single-block exclusive scan -> row_ptr[N+1]
__global__ void k_scan(const int* __restrict__ cnt, int* __restrict__ row_ptr, int N) {
    __shared__ int tmp[256];
    __shared__ int carry_s;
    if (threadIdx.x == 0) { carry_s = 0; row_ptr[0] = 0; }
    __syncthreads();
    for (int base = 0; base < N; base += 256) {
        int i = base + (int)threadIdx.x;
        tmp[threadIdx.x] = (i < N) ? cnt[i] : 0;
        __syncthreads();
        for (int off = 1; off < 256; off <<= 1) {
            int t = (threadIdx.x >= (unsigned)off) ? tmp[threadIdx.x - off] : 0;
            __syncthreads();
            tmp[threadIdx.x] += t;
            __syncthreads();
        }
        int c = carry_s;
        if (i < N) row_ptr[i + 1] = c + tmp[threadIdx.x];
        __syncthreads();
        if (threadIdx.x == 0) carry_s = c + tmp[255];
        __syncthreads();
    }
}

__global__ void k_fill(const int* __restrict__ edst, int* __restrict__ cursor,
                       int* __restrict__ csr_e, int E, int N) {
    int e = blockIdx.x * blockDim.x + threadIdx.x;
    if (e >= E + N) return;
    int d = (e < E) ? edst[e] : (e - E);
    int pos = atomicAdd(&cursor[d], 1);
    csr_e[pos] = e;
}

// C[M,Fo] = A[M,K] * W[Fo,K]^T (+ optional bias). A is f32; W/bias raw (adaptive).
#define BM 64
#define BN 64
#define BKK 16
__global__ void k_gemm_abt(const float* __restrict__ A, const void* __restrict__ W,
                           const void* __restrict__ bias, const int* __restrict__ flags,
                           float* __restrict__ C, int M, int Fo, int K) {
    __shared__ float As[BKK][BM + 1];
    __shared__ float Ws[BKK][BN + 1];
    int isf32 = get_isf32(flags);
    int tid = threadIdx.y * 16 + threadIdx.x;
    int bm = blockIdx.y * BM, bn = blockIdx.x * BN;
    float acc[4][4] = {};
    for (int k0 = 0; k0 < K; k0 += BKK) {
        for (int t = tid; t < BM * BKK; t += 256) {
            int m = t / BKK, kk = t % BKK;
            int gm = bm + m;
            As[kk][m] = (gm < M) ? A[(size_t)gm * K + k0 + kk] : 0.f;
        }
        for (int t = tid; t < BN * BKK; t += 256) {
            int n = t / BKK, kk = t % BKK;
            int gn = bn + n;
            Ws[kk][n] = (gn < Fo) ? loadf(W, (size_t)gn * K + k0 + kk, isf32) : 0.f;
        }
        __syncthreads();
        for (int kk = 0; kk < BKK; ++kk) {
            float a[4], w[4];
#pragma unroll
            for (int i = 0; i < 4; i++) a[i] = As[kk][threadIdx.y * 4 + i];
#pragma unroll
            for (int j = 0; j < 4; j++) w[j] = Ws[kk][threadIdx.x * 4 + j];
#pragma unroll
            for (int i = 0; i < 4; i++)
#pragma unroll
                for (int j = 0; j < 4; j++) acc[i][j] += a[i] * w[j];
        }
        __syncthreads();
    }
    for (int i = 0; i < 4; i++) {
        int gm = bm + threadIdx.y * 4 + i;
        if (gm >= M) continue;
        for (int j = 0; j < 4; j++) {
            int gn = bn + threadIdx.x * 4 + j;
            if (gn >= Fo) continue;
            float v = acc[i][j];
            if (bias) v += loadf(bias, gn, isf32);
            C[(size_t)gm * Fo + gn] = v;
        }
    }
}

// per-(node,head) attention logits
__global__ void k_node_alpha(const float* __restrict__ h, const void* __restrict__ a_s,
                             const void* __restrict__ a_d, const int* __restrict__ flags,
                             float* __restrict__ asrc, float* __restrict__ adst,
                             int N, int H, int C) {
    int i = blockIdx.x * blockDim.x + threadIdx.x;
    if (i >= N * H) return;
    int isf32 = get_isf32(flags);
    int n = i / H, hh = i % H;
    const float* hp = h + (size_t)n * H * C + (size_t)hh * C;
    float s1 = 0.f, s2 = 0.f;
    for (int c = 0; c < C; ++c) {
        float v = hp[c];
        s1 += v * loadf(a_s, hh * C + c, isf32);
        s2 += v * loadf(a_d, hh * C + c, isf32);
    }
    asrc[i] = s1;
    adst[i] = s2;
}

// per-(dst,head) segment softmax over CSR in-edges
__global__ void k_edge_softmax(const int* __restrict__ esrc, const int* __restrict__ row_ptr,
                               const int* __restrict__ csr_e,
                               const float* __restrict__ asrc, const float* __restrict__ adst,
                               float* __restrict__ alpha, int E, int N, int H) {
    int i = blockIdx.x * blockDim.x + threadIdx.x;
    if (i >= N * H) return;
    int d = i / H, hh = i % H;
    int lo = row_ptr[d], hi = row_ptr[d + 1];
    float ad = adst[(size_t)d * H + hh];
    float m = -1e30f;
    for (int p = lo; p < hi; ++p) {
        int e = csr_e[p];
        int s = (e < E) ? esrc[e] : (e - E);
        float v = asrc[(size_t)s * H + hh] + ad;
        v = (v > 0.f) ? v : 0.2f * v;
        alpha[(size_t)e * H + hh] = v;
        m = fmaxf(m, v);
    }
    float ssum = 0.f;
    for (int p = lo; p < hi; ++p) {
        int e = csr_e[p];
        float v = __expf(alpha[(size_t)e * H + hh] - m);
        alpha[(size_t)e * H + hh] = v;
        ssum += v;
    }
    float inv = 1.f / (ssum + 1e-16f);
    for (int p = lo; p < hi; ++p) {
        int e = csr_e[p];
        alpha[(size_t)e * H + hh] *= inv;
    }
}

// one wave per dst node: agg[d,f] = sum_e alpha[e, f/32] * hlin[src(e), f]
// mode 1: out(f32) = elu(agg + bias[f]) + ident[d,f]
// mode 2: layer-3 finish: head-mean + bias[c] + ident[d*32+c] -> out (dtype adaptive)
__global__ void k_aggregate(const float* __restrict__ hlin, const float* __restrict__ alpha,
                            const int* __restrict__ esrc, const int* __restrict__ row_ptr,
                            const int* __restrict__ csr_e,
                            const void* __restrict__ bias, const float* __restrict__ ident,
                            void* __restrict__ out, const int* __restrict__ flags,
                            int E, int N, int H, int C, int mode) {
    int wave = blockIdx.x * (blockDim.x >> 6) + (threadIdx.x >> 6);
    int lane = threadIdx.x & 63;
    if (wave >= N) return;
    int isf32 = get_isf32(flags);
    int d = wave;
    int F = H * C;
    int nj = (F + 63) >> 6;  // 4 (F=256) or 5 (F=320)
    float acc[5] = {0.f, 0.f, 0.f, 0.f, 0.f};
    int lo = row_ptr[d], hi = row_ptr[d + 1];
    for (int p = lo; p < hi; ++p) {
        int e = csr_e[p];
        int s = (e < E) ? esrc[e] : (e - E);
        const float* hp = hlin + (size_t)s * F;
        const float* ap = alpha + (size_t)e * H;
#pragma unroll 5
        for (int j = 0; j < nj; ++j) {
            int f = lane + j * 64;
            if (f < F) acc[j] += ap[f >> 5] * hp[f];
        }
    }
    if (mode == 1) {
        float* o = (float*)out;
#pragma unroll 5
        for (int j = 0; j < nj; ++j) {
            int f = lane + j * 64;
            if (f >= F) break;
            float v = acc[j] + loadf(bias, f, isf32);
            v = (v > 0.f) ? v : (__expf(v) - 1.f);  // ELU
            v += ident[(size_t)d * F + f];
            o[(size_t)d * F + f] = v;
        }
    } else {
        // H=10, F=320. lane's acc[j] holds f = lane+64j -> head = 2j + (lane>>5),
        // channel c = lane & 31 (same c for all j). Partner lane^32 holds the
        // other head parity -> one shfl_xor completes the 10-head sum.
        float s5 = acc[0] + acc[1] + acc[2] + acc[3] + acc[4];
        s5 += __shfl_xor(s5, 32);
        int c = lane & 31;
        float v = s5 * 0.1f + loadf(bias, c, isf32) + ident[(size_t)d * 32 + c];
        if (lane < 32) {
            if (isf32) ((float*)out)[(size_t)d * 32 + c] = v;
            else ((bf16*)out)[(size_t)d * 32 + c] = __float2bfloat16(v);
        }
    }
}

extern "C" void kernel_launch(void* const* d_in, const int* in_sizes, int n_in,
                              void* d_out, int out_size, void* d_ws, size_t ws_size,
                              hipStream_t stream) {
    const int IN = 256, C = 32;
    const int N = in_sizes[0] / IN;
    const int E = in_sizes[1] / 2;
    const int ET = E + N;

    const void* x    = d_in[0];
    const int*  edge = (const int*)d_in[1];
    const void* W1 = d_in[2];
    const void* a1s = d_in[3];
    const void* a1d = d_in[4];
    const void* b1 = d_in[5];
    const void* W2 = d_in[6];
    const void* a2s = d_in[7];
    const void* a2d = d_in[8];
    const void* b2 = d_in[9];
    const void* W3 = d_in[10];
    const void* a3s = d_in[11];
    const void* a3d = d_in[12];
    const void* b3 = d_in[13];
    const void* P1W = d_in[14];
    const void* P1b = d_in[15];
    const void* P3W = d_in[16];
    const void* P3b = d_in[17];

    char* ws = (char*)d_ws;
    size_t off = 0;
    auto alloc = [&](size_t bytes) -> void* {
        void* p = ws + off;
        off = (off + bytes + 255) & ~(size_t)255;
        return p;
    };
    float* fx    = (float*)alloc((size_t)N * 256 * 4);   // normalized input
    float* fh    = (float*)alloc((size_t)N * 320 * 4);   // h_lin (per layer)
    float* fy    = (float*)alloc((size_t)N * 256 * 4);   // layer outputs
    float* fid   = (float*)alloc((size_t)N * 256 * 4);   // identity1 / identity3 (N*32)
    float* fasrc = (float*)alloc((size_t)N * 10 * 4);
    float* fadst = (float*)alloc((size_t)N * 10 * 4);
    float* falpha= (float*)alloc((size_t)ET * 10 * 4);
    int*   isrc  = (int*)alloc((size_t)E * 4);
    int*   idst  = (int*)alloc((size_t)E * 4);
    int*   irow  = (int*)alloc((size_t)(N + 1) * 4);
    int*   icur  = (int*)alloc((size_t)N * 4);
    int*   icsr  = (int*)alloc((size_t)ET * 4);
    int*   flags = (int*)alloc(4 * 4);
    (void)ws_size;

    auto cdiv = [](int a, int b) { return (a + b - 1) / b; };

    // dtype detection + normalization
    k_zero_i<<<1, 64, 0, stream>>>(flags, 4);
    k_detect_x<<<cdiv(N * 256, 256), 256, 0, stream>>>((const unsigned short*)x, flags, N * 256);
    k_detect_e<<<cdiv(2 * E, 256), 256, 0, stream>>>(edge, flags, 2 * E);
    k_norm_x<<<cdiv(N * 256, 256), 256, 0, stream>>>(x, flags, fx, N * 256);
    k_norm_e<<<cdiv(E, 256), 256, 0, stream>>>(edge, flags, isrc, idst, E);

    // CSR over dst (edges + self-loops), shared by all layers
    k_zero_i<<<cdiv(N, 256), 256, 0, stream>>>(icur, N);
    k_count<<<cdiv(ET, 256), 256, 0, stream>>>(idst, icur, E, N);
    k_scan<<<1, 256, 0, stream>>>(icur, irow, N);
    k_copy_i<<<cdiv(N, 256), 256, 0, stream>>>(irow, icur, N);
    k_fill<<<cdiv(ET, 256), 256, 0, stream>>>(idst, icur, icsr, E, N);

    dim3 blk16(16, 16);

    // ---- Layer 1: H=8, F=256 ----
    {
        int H = 8, F = 256;
        k_gemm_abt<<<dim3(cdiv(F, BN), cdiv(N, BM)), blk16, 0, stream>>>(fx, W1, nullptr, flags, fh, N, F, 256);
        k_gemm_abt<<<dim3(cdiv(256, BN), cdiv(N, BM)), blk16, 0, stream>>>(fx, P1W, P1b, flags, fid, N, 256, 256);
        k_node_alpha<<<cdiv(N * H, 256), 256, 0, stream>>>(fh, a1s, a1d, flags, fasrc, fadst, N, H, C);
        k_edge_softmax<<<cdiv(N * H, 256), 256, 0, stream>>>(isrc, irow, icsr, fasrc, fadst, falpha, E, N, H);
        k_aggregate<<<cdiv(N, 4), 256, 0, stream>>>(fh, falpha, isrc, irow, icsr, b1, fid, fy, flags, E, N, H, C, 1);
    }
    // ---- Layer 2: H=8, F=256, identity = layer-1 output (in-place epilogue) ----
    {
        int H = 8, F = 256;
        k_gemm_abt<<<dim3(cdiv(F, BN), cdiv(N, BM)), blk16, 0, stream>>>(fy, W2, nullptr, flags, fh, N, F, 256);
        k_node_alpha<<<cdiv(N * H, 256), 256, 0, stream>>>(fh, a2s, a2d, flags, fasrc, fadst, N, H, C);
        k_edge_softmax<<<cdiv(N * H, 256), 256, 0, stream>>>(isrc, irow, icsr, fasrc, fadst, falpha, E, N, H);
        k_aggregate<<<cdiv(N, 4), 256, 0, stream>>>(fh, falpha, isrc, irow, icsr, b2, fy, fy, flags, E, N, H, C, 1);
    }
    // ---- Layer 3: H=10, concat=False (head-mean fused into aggregate) ----
    {
        int H = 10, F = 320;
        k_gemm_abt<<<dim3(cdiv(F, BN), cdiv(N, BM)), blk16, 0, stream>>>(fy, W3, nullptr, flags, fh, N, F, 256);
        k_gemm_abt<<<dim3(cdiv(32, BN), cdiv(N, BM)), blk16, 0, stream>>>(fy, P3W, P3b, flags, fid, N, 32, 256);
        k_node_alpha<<<cdiv(N * H, 256), 256, 0, stream>>>(fh, a3s, a3d, flags, fasrc, fadst, N, H, C);
        k_edge_softmax<<<cdiv(N * H, 256), 256, 0, stream>>>(isrc, irow, icsr, fasrc, fadst, falpha, E, N, H);
        k_aggregate<<<cdiv(N, 4), 256, 0, stream>>>(fh, falpha, isrc, irow, icsr, b3, fid, d_out, flags, E, N, H, C, 2);
    }
}

// Round 4
// 798.333 us; speedup vs baseline: 1.8359x; 1.8359x over previous
//
#include <hip/hip_runtime.h>
#include <hip/hip_bf16.h>

typedef __hip_bfloat16 bf16;
typedef __attribute__((ext_vector_type(8))) short bf16x8;
typedef __attribute__((ext_vector_type(4))) float f32x4;

// ---------------------------------------------------------------------------
// 3-layer GAT forward. Dtype-adaptive (observed world: floats=bf16, edges=i32).
// flags[0]=1 if NaN/Inf ushort pattern in x-prefix (=> x is f32)
// flags[1]=1 if any odd 32-bit word of edge prefix nonzero (=> edges i32)
// flags[2]=1 if any even-index ushort of x-prefix nonzero
// isf32 = flags[0] || !flags[2]
// ---------------------------------------------------------------------------

static __device__ __forceinline__ float loadf(const void* p, size_t i, int isf32) {
    return isf32 ? ((const float*)p)[i] : __bfloat162float(((const bf16*)p)[i]);
}
static __device__ __forceinline__ int get_isf32(const int* flags) {
    return (flags[0] | (flags[2] == 0)) ? 1 : 0;
}

__global__ void k_zero_i(int* __restrict__ p, int n) {
    int i = blockIdx.x * blockDim.x + threadIdx.x;
    if (i < n) p[i] = 0;
}

// ballot-reduced detection: one atomic per wave, probe prefix only
__global__ void k_detect_x(const unsigned short* __restrict__ u, int* __restrict__ flags, int n) {
    int i = blockIdx.x * blockDim.x + threadIdx.x;
    bool act = i < n;
    unsigned short v = act ? u[i] : (unsigned short)0;
    bool nanp = act && ((v & 0x7F80u) == 0x7F80u);
    bool nz   = act && ((i & 1) == 0) && (v != 0);
    unsigned long long m0 = __ballot(nanp);
    unsigned long long m2 = __ballot(nz);
    if ((threadIdx.x & 63) == 0) {
        if (m0) atomicOr(&flags[0], 1);
        if (m2) atomicOr(&flags[2], 1);
    }
}

__global__ void k_detect_e(const int* __restrict__ w, int* __restrict__ flags, int n2) {
    int i = blockIdx.x * blockDim.x + threadIdx.x;
    bool act = (i < n2) && (i & 1);
    bool nz = act && (w[i] != 0);
    unsigned long long m1 = __ballot(nz);
    if ((threadIdx.x & 63) == 0 && m1) atomicOr(&flags[1], 1);
}

// adaptive cast -> bf16 (identity copy in bf16 world)
__global__ void k_cast_bf16(const void* __restrict__ in, const int* __restrict__ flags,
                            bf16* __restrict__ out, int n) {
    int i = blockIdx.x * blockDim.x + threadIdx.x;
    if (i >= n) return;
    if (get_isf32(flags)) out[i] = __float2bfloat16(((const float*)in)[i]);
    else                  out[i] = ((const bf16*)in)[i];
}

// normalize edges to int32 src/dst arrays
__global__ void k_norm_e(const int* __restrict__ w, const int* __restrict__ flags,
                         int* __restrict__ s, int* __restrict__ d, int E) {
    int e = blockIdx.x * blockDim.x + threadIdx.x;
    if (e >= E) return;
    if (flags[1] == 0) {  // int64
        s[e] = w[2 * (size_t)e];
        d[e] = w[2 * (size_t)E + 2 * (size_t)e];
    } else {              // int32
        s[e] = w[e];
        d[e] = w[(size_t)E + e];
    }
}

__global__ void k_copy_i(const int* __restrict__ a, int* __restrict__ b, int n) {
    int i = blockIdx.x * blockDim.x + threadIdx.x;
    if (i < n) b[i] = a[i];
}

__global__ void k_count(const int* __restrict__ edst, int* __restrict__ cnt, int E, int N) {
    int e = blockIdx.x * blockDim.x + threadIdx.x;
    if (e >= E + N) return;
    int d = (e < E) ? edst[e] : (e - E);
    atomicAdd(&cnt[d], 1);
}

// single-block exclusive scan -> row_ptr[N+1]
__global__ void k_scan(const int* __restrict__ cnt, int* __restrict__ row_ptr, int N) {
    __shared__ int tmp[256];
    __shared__ int carry_s;
    if (threadIdx.x == 0) { carry_s = 0; row_ptr[0] = 0; }
    __syncthreads();
    for (int base = 0; base < N; base += 256) {
        int i = base + (int)threadIdx.x;
        tmp[threadIdx.x] = (i < N) ? cnt[i] : 0;
        __syncthreads();
        for (int off = 1; off < 256; off <<= 1) {
            int t = (threadIdx.x >= (unsigned)off) ? tmp[threadIdx.x - off] : 0;
            __syncthreads();
            tmp[threadIdx.x] += t;
            __syncthreads();
        }
        int c = carry_s;
        if (i < N) row_ptr[i + 1] = c + tmp[threadIdx.x];
        __syncthreads();
        if (threadIdx.x == 0) carry_s = c + tmp[255];
        __syncthreads();
    }
}

__global__ void k_fill(const int* __restrict__ edst, int* __restrict__ cursor,
                       int* __restrict__ csr_e, int E, int N) {
    int e = blockIdx.x * blockDim.x + threadIdx.x;
    if (e >= E + N) return;
    int d = (e < E) ? edst[e] : (e - E);
    int pos = atomicAdd(&cursor[d], 1);
    csr_e[pos] = e;
}

// ---------------------------------------------------------------------------
// MFMA GEMM: C[M,Fo] = A[M,K](bf16) * W[Fo,K](bf16)^T (+bias). K%32==0, M%16==0.
// grid = (ceil(M/64), Fo/(NT*16)), block = 256 (4 waves).
// Wave computes 16 rows x NT*16 cols. Fragment loads direct from global (L2-hot).
// Layout (verified m89/m92): A/B frag lane l: 8 contiguous k at k0+8*(l>>4),
// row/col = l&15. D: col = l&15, row = 4*(l>>4)+reg.
// ---------------------------------------------------------------------------
template<int NT>
__global__ void k_gemm_mfma(const bf16* __restrict__ A, const bf16* __restrict__ W,
                            const void* __restrict__ bias, const int* __restrict__ flags,
                            float* __restrict__ C, int M, int Fo, int K) {
    int wid = threadIdx.x >> 6;
    int lane = threadIdx.x & 63;
    int mrow = blockIdx.x * 64 + wid * 16;
    if (mrow >= M) return;
    int ncol = blockIdx.y * (NT * 16);
    int r = lane & 15, g = lane >> 4;

    f32x4 acc[NT];
#pragma unroll
    for (int t = 0; t < NT; ++t) acc[t] = (f32x4){0.f, 0.f, 0.f, 0.f};

    const bf16* arow = A + (size_t)(mrow + r) * K + g * 8;
    const bf16* wbase = W + (size_t)(ncol + r) * K + g * 8;
    for (int k0 = 0; k0 < K; k0 += 32) {
        bf16x8 af = *(const bf16x8*)(arow + k0);
#pragma unroll
        for (int t = 0; t < NT; ++t) {
            bf16x8 bfr = *(const bf16x8*)(wbase + (size_t)t * 16 * K + k0);
            acc[t] = __builtin_amdgcn_mfma_f32_16x16x32_bf16(af, bfr, acc[t], 0, 0, 0);
        }
    }
    int isf32 = flags ? get_isf32(flags) : 0;
#pragma unroll
    for (int t = 0; t < NT; ++t) {
        int n = ncol + t * 16 + r;
        float bv = bias ? loadf(bias, n, isf32) : 0.f;
#pragma unroll
        for (int j = 0; j < 4; ++j) {
            int m = mrow + 4 * g + j;
            C[(size_t)m * Fo + n] = acc[t][j] + bv;
        }
    }
}

// per-(node,head) attention logits
__global__ void k_node_alpha(const float* __restrict__ h, const void* __restrict__ a_s,
                             const void* __restrict__ a_d, const int* __restrict__ flags,
                             float* __restrict__ asrc, float* __restrict__ adst,
                             int N, int H, int C) {
    int i = blockIdx.x * blockDim.x + threadIdx.x;
    if (i >= N * H) return;
    int isf32 = get_isf32(flags);
    int n = i / H, hh = i % H;
    const float* hp = h + (size_t)n * H * C + (size_t)hh * C;
    float s1 = 0.f, s2 = 0.f;
    for (int c = 0; c < C; ++c) {
        float v = hp[c];
        s1 += v * loadf(a_s, hh * C + c, isf32);
        s2 += v * loadf(a_d, hh * C + c, isf32);
    }
    asrc[i] = s1;
    adst[i] = s2;
}

// per-(dst,head) segment softmax over CSR in-edges
__global__ void k_edge_softmax(const int* __restrict__ esrc, const int* __restrict__ row_ptr,
                               const int* __restrict__ csr_e,
                               const float* __restrict__ asrc, const float* __restrict__ adst,
                               float* __restrict__ alpha, int E, int N, int H) {
    int i = blockIdx.x * blockDim.x + threadIdx.x;
    if (i >= N * H) return;
    int d = i / H, hh = i % H;
    int lo = row_ptr[d], hi = row_ptr[d + 1];
    float ad = adst[(size_t)d * H + hh];
    float m = -1e30f;
    for (int p = lo; p < hi; ++p) {
        int e = csr_e[p];
        int s = (e < E) ? esrc[e] : (e - E);
        float v = asrc[(size_t)s * H + hh] + ad;
        v = (v > 0.f) ? v : 0.2f * v;
        alpha[(size_t)e * H + hh] = v;
        m = fmaxf(m, v);
    }
    float ssum = 0.f;
    for (int p = lo; p < hi; ++p) {
        int e = csr_e[p];
        float v = __expf(alpha[(size_t)e * H + hh] - m);
        alpha[(size_t)e * H + hh] = v;
        ssum += v;
    }
    float inv = 1.f / (ssum + 1e-16f);
    for (int p = lo; p < hi; ++p) {
        int e = csr_e[p];
        alpha[(size_t)e * H + hh] *= inv;
    }
}

// one wave per dst node: agg[d,f] = sum_e alpha[e, f/32] * hlin[src(e), f]
// mode 1: v = elu(agg + bias[f]) + ident[d,f]; write f32 out and bf16 outb
// mode 2: layer-3 head-mean + bias[c] + ident[d*32+c] -> out (dtype adaptive)
__global__ void k_aggregate(const float* __restrict__ hlin, const float* __restrict__ alpha,
                            const int* __restrict__ esrc, const int* __restrict__ row_ptr,
                            const int* __restrict__ csr_e,
                            const void* __restrict__ bias, const float* __restrict__ ident,
                            void* __restrict__ out, bf16* __restrict__ outb,
                            const int* __restrict__ flags,
                            int E, int N, int H, int C, int mode) {
    int wave = blockIdx.x * (blockDim.x >> 6) + (threadIdx.x >> 6);
    int lane = threadIdx.x & 63;
    if (wave >= N) return;
    int isf32 = get_isf32(flags);
    int d = wave;
    int F = H * C;
    int nj = (F + 63) >> 6;  // 4 (F=256) or 5 (F=320)
    float acc[5] = {0.f, 0.f, 0.f, 0.f, 0.f};
    int lo = row_ptr[d], hi = row_ptr[d + 1];
    for (int p = lo; p < hi; ++p) {
        int e = csr_e[p];
        int s = (e < E) ? esrc[e] : (e - E);
        const float* hp = hlin + (size_t)s * F;
        const float* ap = alpha + (size_t)e * H;
#pragma unroll 5
        for (int j = 0; j < nj; ++j) {
            int f = lane + j * 64;
            if (f < F) acc[j] += ap[f >> 5] * hp[f];
        }
    }
    if (mode == 1) {
        float* o = (float*)out;
#pragma unroll 5
        for (int j = 0; j < nj; ++j) {
            int f = lane + j * 64;
            if (f >= F) break;
            float v = acc[j] + loadf(bias, f, isf32);
            v = (v > 0.f) ? v : (__expf(v) - 1.f);  // ELU
            v += ident[(size_t)d * F + f];
            o[(size_t)d * F + f] = v;
            outb[(size_t)d * F + f] = __float2bfloat16(v);
        }
    } else {
        // H=10, F=320: f = lane + 64j -> head 2j + (lane>>5), channel lane&31.
        float s5 = acc[0] + acc[1] + acc[2] + acc[3] + acc[4];
        s5 += __shfl_xor(s5, 32);
        int c = lane & 31;
        float v = s5 * 0.1f + loadf(bias, c, isf32) + ident[(size_t)d * 32 + c];
        if (lane < 32) {
            if (isf32) ((float*)out)[(size_t)d * 32 + c] = v;
            else ((bf16*)out)[(size_t)d * 32 + c] = __float2bfloat16(v);
        }
    }
}

extern "C" void kernel_launch(void* const* d_in, const int* in_sizes, int n_in,
                              void* d_out, int out_size, void* d_ws, size_t ws_size,
                              hipStream_t stream) {
    const int IN = 256, C = 32;
    const int N = in_sizes[0] / IN;
    const int E = in_sizes[1] / 2;
    const int ET = E + N;

    const void* x    = d_in[0];
    const int*  edge = (const int*)d_in[1];
    const void* W1 = d_in[2];
    const void* a1s = d_in[3];
    const void* a1d = d_in[4];
    const void* b1 = d_in[5];
    const void* W2 = d_in[6];
    const void* a2s = d_in[7];
    const void* a2d = d_in[8];
    const void* b2 = d_in[9];
    const void* W3 = d_in[10];
    const void* a3s = d_in[11];
    const void* a3d = d_in[12];
    const void* b3 = d_in[13];
    const void* P1W = d_in[14];
    const void* P1b = d_in[15];
    const void* P3W = d_in[16];
    const void* P3b = d_in[17];

    char* ws = (char*)d_ws;
    size_t off = 0;
    auto alloc = [&](size_t bytes) -> void* {
        void* p = ws + off;
        off = (off + bytes + 255) & ~(size_t)255;
        return p;
    };
    bf16* fxb   = (bf16*)alloc((size_t)N * 256 * 2);    // bf16 input
    bf16* fyb   = (bf16*)alloc((size_t)N * 256 * 2);    // bf16 layer outputs
    float* fh   = (float*)alloc((size_t)N * 320 * 4);   // h_lin (per layer)
    float* fy   = (float*)alloc((size_t)N * 256 * 4);   // f32 layer outputs
    float* fid  = (float*)alloc((size_t)N * 256 * 4);   // identity1 / identity3
    float* fasrc = (float*)alloc((size_t)N * 10 * 4);
    float* fadst = (float*)alloc((size_t)N * 10 * 4);
    float* falpha= (float*)alloc((size_t)ET * 10 * 4);
    bf16* wb1   = (bf16*)alloc((size_t)256 * 256 * 2);
    bf16* wbP1  = (bf16*)alloc((size_t)256 * 256 * 2);
    bf16* wb2   = (bf16*)alloc((size_t)256 * 256 * 2);
    bf16* wb3   = (bf16*)alloc((size_t)320 * 256 * 2);
    bf16* wbP3  = (bf16*)alloc((size_t)32 * 256 * 2);
    int*  isrc  = (int*)alloc((size_t)E * 4);
    int*  idst  = (int*)alloc((size_t)E * 4);
    int*  irow  = (int*)alloc((size_t)(N + 1) * 4);
    int*  icur  = (int*)alloc((size_t)N * 4);
    int*  icsr  = (int*)alloc((size_t)ET * 4);
    int*  flags = (int*)alloc(4 * 4);
    (void)ws_size;

    auto cdiv = [](int a, int b) { return (a + b - 1) / b; };

    // dtype detection (prefix probe, ballot-reduced)
    int nprobe_x = (N * 256 < 262144) ? N * 256 : 262144;
    int nprobe_e = (2 * E < 65536) ? 2 * E : 65536;
    k_zero_i<<<1, 64, 0, stream>>>(flags, 4);
    k_detect_x<<<cdiv(nprobe_x, 256), 256, 0, stream>>>((const unsigned short*)x, flags, nprobe_x);
    k_detect_e<<<cdiv(nprobe_e, 256), 256, 0, stream>>>(edge, flags, nprobe_e);

    // normalize inputs
    k_cast_bf16<<<cdiv(N * 256, 256), 256, 0, stream>>>(x, flags, fxb, N * 256);
    k_cast_bf16<<<cdiv(256 * 256, 256), 256, 0, stream>>>(W1, flags, wb1, 256 * 256);
    k_cast_bf16<<<cdiv(256 * 256, 256), 256, 0, stream>>>(P1W, flags, wbP1, 256 * 256);
    k_cast_bf16<<<cdiv(256 * 256, 256), 256, 0, stream>>>(W2, flags, wb2, 256 * 256);
    k_cast_bf16<<<cdiv(320 * 256, 256), 256, 0, stream>>>(W3, flags, wb3, 320 * 256);
    k_cast_bf16<<<cdiv(32 * 256, 256), 256, 0, stream>>>(P3W, flags, wbP3, 32 * 256);
    k_norm_e<<<cdiv(E, 256), 256, 0, stream>>>(edge, flags, isrc, idst, E);

    // CSR over dst (edges + self-loops)
    k_zero_i<<<cdiv(N, 256), 256, 0, stream>>>(icur, N);
    k_count<<<cdiv(ET, 256), 256, 0, stream>>>(idst, icur, E, N);
    k_scan<<<1, 256, 0, stream>>>(icur, irow, N);
    k_copy_i<<<cdiv(N, 256), 256, 0, stream>>>(irow, icur, N);
    k_fill<<<cdiv(ET, 256), 256, 0, stream>>>(idst, icur, icsr, E, N);

    int gx = cdiv(N, 64);

    // ---- Layer 1: H=8, F=256 ----
    {
        int H = 8;
        k_gemm_mfma<4><<<dim3(gx, 4), 256, 0, stream>>>(fxb, wb1, nullptr, flags, fh, N, 256, 256);
        k_gemm_mfma<4><<<dim3(gx, 4), 256, 0, stream>>>(fxb, wbP1, P1b, flags, fid, N, 256, 256);
        k_node_alpha<<<cdiv(N * H, 256), 256, 0, stream>>>(fh, a1s, a1d, flags, fasrc, fadst, N, H, C);
        k_edge_softmax<<<cdiv(N * H, 256), 256, 0, stream>>>(isrc, irow, icsr, fasrc, fadst, falpha, E, N, H);
        k_aggregate<<<cdiv(N, 4), 256, 0, stream>>>(fh, falpha, isrc, irow, icsr, b1, fid, fy, fyb, flags, E, N, H, C, 1);
    }
    // ---- Layer 2: H=8, F=256, identity = layer-1 output ----
    {
        int H = 8;
        k_gemm_mfma<4><<<dim3(gx, 4), 256, 0, stream>>>(fyb, wb2, nullptr, flags, fh, N, 256, 256);
        k_node_alpha<<<cdiv(N * H, 256), 256, 0, stream>>>(fh, a2s, a2d, flags, fasrc, fadst, N, H, C);
        k_edge_softmax<<<cdiv(N * H, 256), 256, 0, stream>>>(isrc, irow, icsr, fasrc, fadst, falpha, E, N, H);
        k_aggregate<<<cdiv(N, 4), 256, 0, stream>>>(fh, falpha, isrc, irow, icsr, b2, fy, fy, fyb, flags, E, N, H, C, 1);
    }
    // ---- Layer 3: H=10, concat=False (head-mean fused) ----
    {
        int H = 10;
        k_gemm_mfma<4><<<dim3(gx, 5), 256, 0, stream>>>(fyb, wb3, nullptr, flags, fh, N, 320, 256);
        k_gemm_mfma<2><<<dim3(gx, 1), 256, 0, stream>>>(fyb, wbP3, P3b, flags, fid, N, 32, 256);
        k_node_alpha<<<cdiv(N * H, 256), 256, 0, stream>>>(fh, a3s, a3d, flags, fasrc, fadst, N, H, C);
        k_edge_softmax<<<cdiv(N * H, 256), 256, 0, stream>>>(isrc, irow, icsr, fasrc, fadst, falpha, E, N, H);
        k_aggregate<<<cdiv(N, 4), 256, 0, stream>>>(fh, falpha, isrc, irow, icsr, b3, fid, d_out, nullptr, flags, E, N, H, C, 2);
    }
}

// Round 5
// 553.962 us; speedup vs baseline: 2.6458x; 1.4411x over previous
//
#include <hip/hip_runtime.h>
#include <hip/hip_bf16.h>

typedef __hip_bfloat16 bf16;
typedef __attribute__((ext_vector_type(8))) short bf16x8;
typedef __attribute__((ext_vector_type(4))) float f32x4;

// ---------------------------------------------------------------------------
// 3-layer GAT forward. Dtype-adaptive (observed world: floats=bf16, edges=i32).
// flags[0]=1 if NaN/Inf ushort pattern in x-prefix (=> x is f32)
// flags[1]=1 if any odd 32-bit word of edge prefix nonzero (=> edges i32)
// flags[2]=1 if any even-index ushort of x-prefix nonzero
// isf32 = flags[0] || !flags[2]
// ---------------------------------------------------------------------------

static __device__ __forceinline__ float bf2f(bf16 v) { return __bfloat162float(v); }
static __device__ __forceinline__ float loadf(const void* p, size_t i, int isf32) {
    return isf32 ? ((const float*)p)[i] : bf2f(((const bf16*)p)[i]);
}
static __device__ __forceinline__ int get_isf32(const int* flags) {
    return (flags[0] | (flags[2] == 0)) ? 1 : 0;
}

__global__ void k_zero_i(int* __restrict__ p, int n) {
    int i = blockIdx.x * blockDim.x + threadIdx.x;
    if (i < n) p[i] = 0;
}

// ballot-reduced detection: one atomic per wave, probe prefix only
__global__ void k_detect_x(const unsigned short* __restrict__ u, int* __restrict__ flags, int n) {
    int i = blockIdx.x * blockDim.x + threadIdx.x;
    bool act = i < n;
    unsigned short v = act ? u[i] : (unsigned short)0;
    bool nanp = act && ((v & 0x7F80u) == 0x7F80u);
    bool nz   = act && ((i & 1) == 0) && (v != 0);
    unsigned long long m0 = __ballot(nanp);
    unsigned long long m2 = __ballot(nz);
    if ((threadIdx.x & 63) == 0) {
        if (m0) atomicOr(&flags[0], 1);
        if (m2) atomicOr(&flags[2], 1);
    }
}

__global__ void k_detect_e(const int* __restrict__ w, int* __restrict__ flags, int n2) {
    int i = blockIdx.x * blockDim.x + threadIdx.x;
    bool act = (i < n2) && (i & 1);
    bool nz = act && (w[i] != 0);
    unsigned long long m1 = __ballot(nz);
    if ((threadIdx.x & 63) == 0 && m1) atomicOr(&flags[1], 1);
}

// adaptive cast -> bf16 (identity copy in bf16 world)
__global__ void k_cast_bf16(const void* __restrict__ in, const int* __restrict__ flags,
                            bf16* __restrict__ out, int n) {
    int i = blockIdx.x * blockDim.x + threadIdx.x;
    if (i >= n) return;
    if (get_isf32(flags)) out[i] = __float2bfloat16(((const float*)in)[i]);
    else                  out[i] = ((const bf16*)in)[i];
}

// normalize edges to int32 src/dst arrays
__global__ void k_norm_e(const int* __restrict__ w, const int* __restrict__ flags,
                         int* __restrict__ s, int* __restrict__ d, int E) {
    int e = blockIdx.x * blockDim.x + threadIdx.x;
    if (e >= E) return;
    if (flags[1] == 0) {  // int64
        s[e] = w[2 * (size_t)e];
        d[e] = w[2 * (size_t)E + 2 * (size_t)e];
    } else {              // int32
        s[e] = w[e];
        d[e] = w[(size_t)E + e];
    }
}

__global__ void k_copy_i(const int* __restrict__ a, int* __restrict__ b, int n) {
    int i = blockIdx.x * blockDim.x + threadIdx.x;
    if (i < n) b[i] = a[i];
}

__global__ void k_count(const int* __restrict__ edst, int* __restrict__ cnt, int E, int N) {
    int e = blockIdx.x * blockDim.x + threadIdx.x;
    if (e >= E + N) return;
    int d = (e < E) ? edst[e] : (e - E);
    atomicAdd(&cnt[d], 1);
}

// single-block exclusive scan -> row_ptr[N+1]
__global__ void k_scan(const int* __restrict__ cnt, int* __restrict__ row_ptr, int N) {
    __shared__ int tmp[256];
    __shared__ int carry_s;
    if (threadIdx.x == 0) { carry_s = 0; row_ptr[0] = 0; }
    __syncthreads();
    for (int base = 0; base < N; base += 256) {
        int i = base + (int)threadIdx.x;
        tmp[threadIdx.x] = (i < N) ? cnt[i] : 0;
        __syncthreads();
        for (int off = 1; off < 256; off <<= 1) {
            int t = (threadIdx.x >= (unsigned)off) ? tmp[threadIdx.x - off] : 0;
            __syncthreads();
            tmp[threadIdx.x] += t;
            __syncthreads();
        }
        int c = carry_s;
        if (i < N) row_ptr[i + 1] = c + tmp[threadIdx.x];
        __syncthreads();
        if (threadIdx.x == 0) carry_s = c + tmp[255];
        __syncthreads();
    }
}

__global__ void k_fill(const int* __restrict__ edst, int* __restrict__ cursor,
                       int* __restrict__ csr_e, int E, int N) {
    int e = blockIdx.x * blockDim.x + threadIdx.x;
    if (e >= E + N) return;
    int d = (e < E) ? edst[e] : (e - E);
    int pos = atomicAdd(&cursor[d], 1);
    csr_e[pos] = e;
}

// ---------------------------------------------------------------------------
// MFMA GEMM: C[M,Fo] = A[M,K](bf16) * W[Fo,K](bf16)^T (+bias). K%32==0.
// grid = (ceil(M/64), Fo/(NT*16)), block = 256 (4 waves).
// OB=true -> bf16 output, else f32.
// ---------------------------------------------------------------------------
template<int NT, bool OB>
__global__ void k_gemm_mfma(const bf16* __restrict__ A, const bf16* __restrict__ W,
                            const void* __restrict__ bias, const int* __restrict__ flags,
                            void* __restrict__ Cp, int M, int Fo, int K) {
    int wid = threadIdx.x >> 6;
    int lane = threadIdx.x & 63;
    int mrow = blockIdx.x * 64 + wid * 16;
    if (mrow >= M) return;
    int ncol = blockIdx.y * (NT * 16);
    int r = lane & 15, g = lane >> 4;

    f32x4 acc[NT];
#pragma unroll
    for (int t = 0; t < NT; ++t) acc[t] = (f32x4){0.f, 0.f, 0.f, 0.f};

    const bf16* arow = A + (size_t)(mrow + r) * K + g * 8;
    const bf16* wbase = W + (size_t)(ncol + r) * K + g * 8;
    for (int k0 = 0; k0 < K; k0 += 32) {
        bf16x8 af = *(const bf16x8*)(arow + k0);
#pragma unroll
        for (int t = 0; t < NT; ++t) {
            bf16x8 bfr = *(const bf16x8*)(wbase + (size_t)t * 16 * K + k0);
            acc[t] = __builtin_amdgcn_mfma_f32_16x16x32_bf16(af, bfr, acc[t], 0, 0, 0);
        }
    }
    int isf32 = flags ? get_isf32(flags) : 0;
#pragma unroll
    for (int t = 0; t < NT; ++t) {
        int n = ncol + t * 16 + r;
        float bv = bias ? loadf(bias, n, isf32) : 0.f;
#pragma unroll
        for (int j = 0; j < 4; ++j) {
            int m = mrow + 4 * g + j;
            float v = acc[t][j] + bv;
            if (OB) ((bf16*)Cp)[(size_t)m * Fo + n] = __float2bfloat16(v);
            else    ((float*)Cp)[(size_t)m * Fo + n] = v;
        }
    }
}

// per-(node,head) attention logits (h in bf16)
__global__ void k_node_alpha(const bf16* __restrict__ h, const void* __restrict__ a_s,
                             const void* __restrict__ a_d, const int* __restrict__ flags,
                             float* __restrict__ asrc, float* __restrict__ adst,
                             int N, int H, int C) {
    int i = blockIdx.x * blockDim.x + threadIdx.x;
    if (i >= N * H) return;
    int isf32 = get_isf32(flags);
    int n = i / H, hh = i % H;
    const bf16* hp = h + (size_t)n * H * C + (size_t)hh * C;
    float s1 = 0.f, s2 = 0.f;
    for (int c = 0; c < C; ++c) {
        float v = bf2f(hp[c]);
        s1 += v * loadf(a_s, hh * C + c, isf32);
        s2 += v * loadf(a_d, hh * C + c, isf32);
    }
    asrc[i] = s1;
    adst[i] = s2;
}

// ---------------------------------------------------------------------------
// Fused per-dst-node softmax + aggregation. One wave per dst node, 4 waves/blk.
// Pass A: gather logits e=leakyrelu(asrc[s][h]+adst[d][h]) into LDS (all heads).
// Pass M: per-head max -> exp -> sum -> 1/(sum+1e-16) in LDS.
// Pass B: acc[f] = sum_p exp_p[head(f)] * h_bf16[s_p][f]; scale by invden.
// mode 1: v = elu(acc + bias[f]) + ident[d,f] -> fy(f32) + fyb(bf16)
// mode 2: head-mean + bias[c] + ident[d*32+c] -> out (dtype adaptive)
// Degree > CAP: slow recompute path (no LDS caching).
// ---------------------------------------------------------------------------
#define CAP 96
__global__ void k_fused_agg(const bf16* __restrict__ hlin,
                            const float* __restrict__ asrc, const float* __restrict__ adst,
                            const int* __restrict__ esrc, const int* __restrict__ row_ptr,
                            const int* __restrict__ csr_e,
                            const void* __restrict__ bias, const float* __restrict__ ident,
                            void* __restrict__ out, bf16* __restrict__ outb,
                            const int* __restrict__ flags,
                            int E, int N, int H, int mode) {
    __shared__ float el[4][CAP * 10];
    __shared__ int   ssrc[4][CAP];
    __shared__ float idn[4][10];
    int wid = threadIdx.x >> 6, lane = threadIdx.x & 63;
    int d = blockIdx.x * 4 + wid;
    bool active = d < N;
    int isf32 = get_isf32(flags);
    int F = H * 32;
    int nj = (F + 63) >> 6;  // 4 or 5
    int lo = 0, deg = 0;
    if (active) { lo = row_ptr[d]; deg = row_ptr[d + 1] - lo; }
    bool fast = deg <= CAP;

    // ---- Pass A: logits into LDS ----
    if (active && fast) {
        int EC = 64 / H;              // edges per chunk (8 for H=8, 6 for H=10)
        int h = lane % H, ei = lane / H;
        float ad = adst[(size_t)d * H + h];
        for (int base = 0; base < deg; base += EC) {
            int p = base + ei;
            if (ei < EC && p < deg) {
                int e = csr_e[lo + p];
                int s = (e < E) ? esrc[e] : (e - E);
                float v = asrc[(size_t)s * H + h] + ad;
                v = (v > 0.f) ? v : 0.2f * v;
                el[wid][p * H + h] = v;
                if (h == 0) ssrc[wid][p] = s;
            }
        }
    }
    __syncthreads();
    // ---- Pass M: per-head softmax normalization ----
    if (active && fast && lane < H) {
        float m = -1e30f;
        for (int p = 0; p < deg; ++p) m = fmaxf(m, el[wid][p * H + lane]);
        float den = 0.f;
        for (int p = 0; p < deg; ++p) {
            float t = __expf(el[wid][p * H + lane] - m);
            el[wid][p * H + lane] = t;
            den += t;
        }
        idn[wid][lane] = 1.f / (den + 1e-16f);
    }
    __syncthreads();

    float acc[5] = {0.f, 0.f, 0.f, 0.f, 0.f};
    if (active) {
        if (fast) {
            for (int p = 0; p < deg; ++p) {
                int s = ssrc[wid][p];
                const bf16* hp = hlin + (size_t)s * F;
#pragma unroll 5
                for (int j = 0; j < nj; ++j) {
                    int f = lane + 64 * j;
                    if (f < F) acc[j] += el[wid][p * H + (f >> 5)] * bf2f(hp[f]);
                }
            }
#pragma unroll 5
            for (int j = 0; j < nj; ++j) {
                int f = lane + 64 * j;
                if (f < F) acc[j] *= idn[wid][f >> 5];
            }
        } else {
            // slow path: recompute logits per lane-head (deg > CAP, rare)
            for (int j = 0; j < nj; ++j) {
                int f = lane + 64 * j;
                if (f >= F) break;
                int hj = f >> 5;
                float ad = adst[(size_t)d * H + hj];
                float m = -1e30f;
                for (int p = 0; p < deg; ++p) {
                    int e = csr_e[lo + p];
                    int s = (e < E) ? esrc[e] : (e - E);
                    float v = asrc[(size_t)s * H + hj] + ad;
                    v = (v > 0.f) ? v : 0.2f * v;
                    m = fmaxf(m, v);
                }
                float den = 0.f, a = 0.f;
                for (int p = 0; p < deg; ++p) {
                    int e = csr_e[lo + p];
                    int s = (e < E) ? esrc[e] : (e - E);
                    float v = asrc[(size_t)s * H + hj] + ad;
                    v = (v > 0.f) ? v : 0.2f * v;
                    float t = __expf(v - m);
                    den += t;
                    a += t * bf2f(hlin[(size_t)s * F + f]);
                }
                acc[j] = a / (den + 1e-16f);
            }
        }
        // ---- epilogue ----
        if (mode == 1) {
            float* o = (float*)out;
#pragma unroll 5
            for (int j = 0; j < nj; ++j) {
                int f = lane + 64 * j;
                if (f >= F) break;
                float v = acc[j] + loadf(bias, f, isf32);
                v = (v > 0.f) ? v : (__expf(v) - 1.f);  // ELU
                v += ident[(size_t)d * F + f];
                o[(size_t)d * F + f] = v;
                outb[(size_t)d * F + f] = __float2bfloat16(v);
            }
        } else {
            // H=10, F=320: f = lane + 64j -> head 2j + (lane>>5), channel lane&31.
            float s5 = acc[0] + acc[1] + acc[2] + acc[3] + acc[4];
            s5 += __shfl_xor(s5, 32);
            int c = lane & 31;
            float v = s5 * 0.1f + loadf(bias, c, isf32) + ident[(size_t)d * 32 + c];
            if (lane < 32) {
                if (isf32) ((float*)out)[(size_t)d * 32 + c] = v;
                else ((bf16*)out)[(size_t)d * 32 + c] = __float2bfloat16(v);
            }
        }
    }
}

extern "C" void kernel_launch(void* const* d_in, const int* in_sizes, int n_in,
                              void* d_out, int out_size, void* d_ws, size_t ws_size,
                              hipStream_t stream) {
    const int IN = 256, C = 32;
    const int N = in_sizes[0] / IN;
    const int E = in_sizes[1] / 2;
    const int ET = E + N;

    const void* x    = d_in[0];
    const int*  edge = (const int*)d_in[1];
    const void* W1 = d_in[2];
    const void* a1s = d_in[3];
    const void* a1d = d_in[4];
    const void* b1 = d_in[5];
    const void* W2 = d_in[6];
    const void* a2s = d_in[7];
    const void* a2d = d_in[8];
    const void* b2 = d_in[9];
    const void* W3 = d_in[10];
    const void* a3s = d_in[11];
    const void* a3d = d_in[12];
    const void* b3 = d_in[13];
    const void* P1W = d_in[14];
    const void* P1b = d_in[15];
    const void* P3W = d_in[16];
    const void* P3b = d_in[17];

    char* ws = (char*)d_ws;
    size_t off = 0;
    auto alloc = [&](size_t bytes) -> void* {
        void* p = ws + off;
        off = (off + bytes + 255) & ~(size_t)255;
        return p;
    };
    bf16* fxb   = (bf16*)alloc((size_t)N * 256 * 2);    // bf16 input
    bf16* fyb   = (bf16*)alloc((size_t)N * 256 * 2);    // bf16 layer outputs
    bf16* fhb   = (bf16*)alloc((size_t)N * 320 * 2);    // h_lin bf16 (per layer)
    float* fy   = (float*)alloc((size_t)N * 256 * 4);   // f32 layer outputs
    float* fid  = (float*)alloc((size_t)N * 256 * 4);   // identity1 / identity3
    float* fasrc = (float*)alloc((size_t)N * 10 * 4);
    float* fadst = (float*)alloc((size_t)N * 10 * 4);
    bf16* wb1   = (bf16*)alloc((size_t)256 * 256 * 2);
    bf16* wbP1  = (bf16*)alloc((size_t)256 * 256 * 2);
    bf16* wb2   = (bf16*)alloc((size_t)256 * 256 * 2);
    bf16* wb3   = (bf16*)alloc((size_t)320 * 256 * 2);
    bf16* wbP3  = (bf16*)alloc((size_t)32 * 256 * 2);
    int*  isrc  = (int*)alloc((size_t)E * 4);
    int*  idst  = (int*)alloc((size_t)E * 4);
    int*  irow  = (int*)alloc((size_t)(N + 1) * 4);
    int*  icur  = (int*)alloc((size_t)N * 4);
    int*  icsr  = (int*)alloc((size_t)ET * 4);
    int*  flags = (int*)alloc(4 * 4);
    (void)ws_size;

    auto cdiv = [](int a, int b) { return (a + b - 1) / b; };

    // dtype detection (prefix probe, ballot-reduced)
    int nprobe_x = (N * 256 < 262144) ? N * 256 : 262144;
    int nprobe_e = (2 * E < 65536) ? 2 * E : 65536;
    k_zero_i<<<1, 64, 0, stream>>>(flags, 4);
    k_detect_x<<<cdiv(nprobe_x, 256), 256, 0, stream>>>((const unsigned short*)x, flags, nprobe_x);
    k_detect_e<<<cdiv(nprobe_e, 256), 256, 0, stream>>>(edge, flags, nprobe_e);

    // normalize inputs
    k_cast_bf16<<<cdiv(N * 256, 256), 256, 0, stream>>>(x, flags, fxb, N * 256);
    k_cast_bf16<<<cdiv(256 * 256, 256), 256, 0, stream>>>(W1, flags, wb1, 256 * 256);
    k_cast_bf16<<<cdiv(256 * 256, 256), 256, 0, stream>>>(P1W, flags, wbP1, 256 * 256);
    k_cast_bf16<<<cdiv(256 * 256, 256), 256, 0, stream>>>(W2, flags, wb2, 256 * 256);
    k_cast_bf16<<<cdiv(320 * 256, 256), 256, 0, stream>>>(W3, flags, wb3, 320 * 256);
    k_cast_bf16<<<cdiv(32 * 256, 256), 256, 0, stream>>>(P3W, flags, wbP3, 32 * 256);
    k_norm_e<<<cdiv(E, 256), 256, 0, stream>>>(edge, flags, isrc, idst, E);

    // CSR over dst (edges + self-loops)
    k_zero_i<<<cdiv(N, 256), 256, 0, stream>>>(icur, N);
    k_count<<<cdiv(ET, 256), 256, 0, stream>>>(idst, icur, E, N);
    k_scan<<<1, 256, 0, stream>>>(icur, irow, N);
    k_copy_i<<<cdiv(N, 256), 256, 0, stream>>>(irow, icur, N);
    k_fill<<<cdiv(ET, 256), 256, 0, stream>>>(idst, icur, icsr, E, N);

    int gx = cdiv(N, 64);
    int ga = cdiv(N, 4);

    // ---- Layer 1: H=8, F=256 ----
    {
        int H = 8;
        k_gemm_mfma<4, true><<<dim3(gx, 4), 256, 0, stream>>>(fxb, wb1, nullptr, flags, fhb, N, 256, 256);
        k_gemm_mfma<4, false><<<dim3(gx, 4), 256, 0, stream>>>(fxb, wbP1, P1b, flags, fid, N, 256, 256);
        k_node_alpha<<<cdiv(N * H, 256), 256, 0, stream>>>(fhb, a1s, a1d, flags, fasrc, fadst, N, H, C);
        k_fused_agg<<<ga, 256, 0, stream>>>(fhb, fasrc, fadst, isrc, irow, icsr, b1, fid, fy, fyb, flags, E, N, H, 1);
    }
    // ---- Layer 2: H=8, F=256, identity = layer-1 output ----
    {
        int H = 8;
        k_gemm_mfma<4, true><<<dim3(gx, 4), 256, 0, stream>>>(fyb, wb2, nullptr, flags, fhb, N, 256, 256);
        k_node_alpha<<<cdiv(N * H, 256), 256, 0, stream>>>(fhb, a2s, a2d, flags, fasrc, fadst, N, H, C);
        k_fused_agg<<<ga, 256, 0, stream>>>(fhb, fasrc, fadst, isrc, irow, icsr, b2, fy, fy, fyb, flags, E, N, H, 1);
    }
    // ---- Layer 3: H=10, concat=False (head-mean fused) ----
    {
        int H = 10;
        k_gemm_mfma<4, true><<<dim3(gx, 5), 256, 0, stream>>>(fyb, wb3, nullptr, flags, fhb, N, 320, 256);
        k_gemm_mfma<2, false><<<dim3(gx, 1), 256, 0, stream>>>(fyb, wbP3, P3b, flags, fid, N, 32, 256);
        k_node_alpha<<<cdiv(N * H, 256), 256, 0, stream>>>(fhb, a3s, a3d, flags, fasrc, fadst, N, H, C);
        k_fused_agg<<<ga, 256, 0, stream>>>(fhb, fasrc, fadst, isrc, irow, icsr, b3, fid, d_out, nullptr, flags, E, N, H, 2);
    }
}

// Round 6
// 384.710 us; speedup vs baseline: 3.8099x; 1.4399x over previous
//
#include <hip/hip_runtime.h>
#include <hip/hip_bf16.h>

typedef __hip_bfloat16 bf16;
typedef __attribute__((ext_vector_type(8))) short bf16x8;
typedef __attribute__((ext_vector_type(4))) short bf16x4;
typedef __attribute__((ext_vector_type(4))) float f32x4;

// ---------------------------------------------------------------------------
// 3-layer GAT forward. Dtype-adaptive (observed world: floats=bf16, edges=i32).
// flags[0]=1 if NaN/Inf ushort pattern in x-prefix (=> x is f32)
// flags[1]=1 if any odd 32-bit word of edge prefix nonzero (=> edges i32)
// flags[2]=1 if any even-index ushort of x-prefix nonzero
// isf32 = flags[0] || !flags[2]
// ---------------------------------------------------------------------------

static __device__ __forceinline__ float bf2f(bf16 v) { return __bfloat162float(v); }
static __device__ __forceinline__ float bf2fs(short v) {
    unsigned int u = ((unsigned int)(unsigned short)v) << 16;
    return __builtin_bit_cast(float, u);
}
static __device__ __forceinline__ short f2bfs(float f) {
    bf16 b = __float2bfloat16(f);
    return __builtin_bit_cast(short, b);
}
static __device__ __forceinline__ float loadf(const void* p, size_t i, int isf32) {
    return isf32 ? ((const float*)p)[i] : bf2f(((const bf16*)p)[i]);
}
static __device__ __forceinline__ int get_isf32(const int* flags) {
    return (flags[0] | (flags[2] == 0)) ? 1 : 0;
}

// merged detection: blocks [0,bx) probe x, rest probe edges; ballot-reduced
__global__ void k_detect(const unsigned short* __restrict__ xu, const int* __restrict__ ew,
                         int* __restrict__ flags, int nx, int ne2, int bx) {
    if ((int)blockIdx.x < bx) {
        int i = blockIdx.x * 256 + threadIdx.x;
        bool act = i < nx;
        unsigned short v = act ? xu[i] : (unsigned short)0;
        bool nanp = act && ((v & 0x7F80u) == 0x7F80u);
        bool nz   = act && ((i & 1) == 0) && (v != 0);
        unsigned long long m0 = __ballot(nanp);
        unsigned long long m2 = __ballot(nz);
        if ((threadIdx.x & 63) == 0) {
            if (m0) atomicOr(&flags[0], 1);
            if (m2) atomicOr(&flags[2], 1);
        }
    } else {
        int i = (blockIdx.x - bx) * 256 + threadIdx.x;
        bool act = (i < ne2) && (i & 1);
        bool nz = act && (ew[i] != 0);
        unsigned long long m1 = __ballot(nz);
        if ((threadIdx.x & 63) == 0 && m1) atomicOr(&flags[1], 1);
    }
}

// 8-elem vectorized adaptive cast
static __device__ __forceinline__ void cast8(const void* src, bf16* dst, int i8, int isf32) {
    if (isf32) {
        f32x4 a = ((const f32x4*)src)[2 * i8];
        f32x4 b = ((const f32x4*)src)[2 * i8 + 1];
        bf16x8 o;
        o[0] = f2bfs(a[0]); o[1] = f2bfs(a[1]); o[2] = f2bfs(a[2]); o[3] = f2bfs(a[3]);
        o[4] = f2bfs(b[0]); o[5] = f2bfs(b[1]); o[6] = f2bfs(b[2]); o[7] = f2bfs(b[3]);
        ((bf16x8*)dst)[i8] = o;
    } else {
        ((bf16x8*)dst)[i8] = ((const bf16x8*)src)[i8];
    }
}

// all input casts in one launch (counts are in 8-elem units)
__global__ void k_cast_all(const void* s0, bf16* d0, int c0,
                           const void* s1, bf16* d1, int c1,
                           const void* s2, bf16* d2, int c2,
                           const void* s3, bf16* d3, int c3,
                           const void* s4, bf16* d4, int c4,
                           const void* s5, bf16* d5, int c5,
                           const int* __restrict__ flags) {
    int t = blockIdx.x * blockDim.x + threadIdx.x;
    int isf32 = get_isf32(flags);
    if (t < c0) { cast8(s0, d0, t, isf32); return; } t -= c0;
    if (t < c1) { cast8(s1, d1, t, isf32); return; } t -= c1;
    if (t < c2) { cast8(s2, d2, t, isf32); return; } t -= c2;
    if (t < c3) { cast8(s3, d3, t, isf32); return; } t -= c3;
    if (t < c4) { cast8(s4, d4, t, isf32); return; } t -= c4;
    if (t < c5) { cast8(s5, d5, t, isf32); }
}

// normalize edges to int32 src/dst arrays
__global__ void k_norm_e(const int* __restrict__ w, const int* __restrict__ flags,
                         int* __restrict__ s, int* __restrict__ d, int E) {
    int e = blockIdx.x * blockDim.x + threadIdx.x;
    if (e >= E) return;
    if (flags[1] == 0) {  // int64
        s[e] = w[2 * (size_t)e];
        d[e] = w[2 * (size_t)E + 2 * (size_t)e];
    } else {              // int32
        s[e] = w[e];
        d[e] = w[(size_t)E + e];
    }
}

__global__ void k_copy_i(const int* __restrict__ a, int* __restrict__ b, int n) {
    int i = blockIdx.x * blockDim.x + threadIdx.x;
    if (i < n) b[i] = a[i];
}

__global__ void k_count(const int* __restrict__ edst, int* __restrict__ cnt, int E, int N) {
    int e = blockIdx.x * blockDim.x + threadIdx.x;
    if (e >= E + N) return;
    int d = (e < E) ? edst[e] : (e - E);
    atomicAdd(&cnt[d], 1);
}

// single-block exclusive scan -> row_ptr[N+1]
__global__ void k_scan(const int* __restrict__ cnt, int* __restrict__ row_ptr, int N) {
    __shared__ int tmp[256];
    __shared__ int carry_s;
    if (threadIdx.x == 0) { carry_s = 0; row_ptr[0] = 0; }
    __syncthreads();
    for (int base = 0; base < N; base += 256) {
        int i = base + (int)threadIdx.x;
        tmp[threadIdx.x] = (i < N) ? cnt[i] : 0;
        __syncthreads();
        for (int off = 1; off < 256; off <<= 1) {
            int t = (threadIdx.x >= (unsigned)off) ? tmp[threadIdx.x - off] : 0;
            __syncthreads();
            tmp[threadIdx.x] += t;
            __syncthreads();
        }
        int c = carry_s;
        if (i < N) row_ptr[i + 1] = c + tmp[threadIdx.x];
        __syncthreads();
        if (threadIdx.x == 0) carry_s = c + tmp[255];
        __syncthreads();
    }
}

__global__ void k_fill(const int* __restrict__ edst, int* __restrict__ cursor,
                       int* __restrict__ csr_e, int E, int N) {
    int e = blockIdx.x * blockDim.x + threadIdx.x;
    if (e >= E + N) return;
    int d = (e < E) ? edst[e] : (e - E);
    int pos = atomicAdd(&cursor[d], 1);
    csr_e[pos] = e;
}

// ---------------------------------------------------------------------------
// MFMA GEMM: C[M,Fo] = A[M,K](bf16) * W[Fo,K](bf16)^T (+bias). K%32==0.
// grid = (ceil(M/64), Fo/(NT*16)), block = 256 (4 waves).
// OB=true -> bf16 output, else f32.
// ---------------------------------------------------------------------------
template<int NT, bool OB>
__global__ void k_gemm_mfma(const bf16* __restrict__ A, const bf16* __restrict__ W,
                            const void* __restrict__ bias, const int* __restrict__ flags,
                            void* __restrict__ Cp, int M, int Fo, int K) {
    int wid = threadIdx.x >> 6;
    int lane = threadIdx.x & 63;
    int mrow = blockIdx.x * 64 + wid * 16;
    if (mrow >= M) return;
    int ncol = blockIdx.y * (NT * 16);
    int r = lane & 15, g = lane >> 4;

    f32x4 acc[NT];
#pragma unroll
    for (int t = 0; t < NT; ++t) acc[t] = (f32x4){0.f, 0.f, 0.f, 0.f};

    const bf16* arow = A + (size_t)(mrow + r) * K + g * 8;
    const bf16* wbase = W + (size_t)(ncol + r) * K + g * 8;
    for (int k0 = 0; k0 < K; k0 += 32) {
        bf16x8 af = *(const bf16x8*)(arow + k0);
#pragma unroll
        for (int t = 0; t < NT; ++t) {
            bf16x8 bfr = *(const bf16x8*)(wbase + (size_t)t * 16 * K + k0);
            acc[t] = __builtin_amdgcn_mfma_f32_16x16x32_bf16(af, bfr, acc[t], 0, 0, 0);
        }
    }
    int isf32 = flags ? get_isf32(flags) : 0;
#pragma unroll
    for (int t = 0; t < NT; ++t) {
        int n = ncol + t * 16 + r;
        float bv = bias ? loadf(bias, n, isf32) : 0.f;
#pragma unroll
        for (int j = 0; j < 4; ++j) {
            int m = mrow + 4 * g + j;
            float v = acc[t][j] + bv;
            if (OB) ((bf16*)Cp)[(size_t)m * Fo + n] = __float2bfloat16(v);
            else    ((float*)Cp)[(size_t)m * Fo + n] = v;
        }
    }
}

// per-(node,head) attention logits (h in bf16, vectorized loads)
__global__ void k_node_alpha(const bf16* __restrict__ h, const void* __restrict__ a_s,
                             const void* __restrict__ a_d, const int* __restrict__ flags,
                             float* __restrict__ asrc, float* __restrict__ adst,
                             int N, int H, int C) {
    int i = blockIdx.x * blockDim.x + threadIdx.x;
    if (i >= N * H) return;
    int isf32 = get_isf32(flags);
    int n = i / H, hh = i % H;
    const bf16x8* hp8 = (const bf16x8*)(h + (size_t)n * H * C + (size_t)hh * C);
    float s1 = 0.f, s2 = 0.f;
#pragma unroll
    for (int c8 = 0; c8 < 4; ++c8) {
        bf16x8 hv = hp8[c8];
#pragma unroll
        for (int k = 0; k < 8; ++k) {
            float v = bf2fs(hv[k]);
            int c = c8 * 8 + k;
            s1 += v * loadf(a_s, hh * C + c, isf32);
            s2 += v * loadf(a_d, hh * C + c, isf32);
        }
    }
    asrc[i] = s1;
    adst[i] = s2;
}

// ---------------------------------------------------------------------------
// Fused per-dst-node softmax + aggregation. One wave per dst node, 4 waves/blk.
// Lane owns 4 consecutive channels: f0 = (lane + 64j)*4  (nj=1 for F=256,
// nj=2 with lanes<16 active for F=320). Gather loads are 8B bf16x4.
// Pass A: logits into LDS. Pass M: per-head max/exp/sum. Pass B: weighted
// gather of unnormalized exp, scale by 1/(den+1e-16) at the end.
// mode 1: v = elu(acc + bias[f]) + ident[d,f] -> fy(f32, float4) + fyb(bf16x4)
// mode 2: head-mean via per-wave LDS scratch (reuses el) -> out dtype adaptive
// Degree > CAP: slow recompute path.
// ---------------------------------------------------------------------------
#define CAP 96
__global__ void k_fused_agg(const bf16* __restrict__ hlin,
                            const float* __restrict__ asrc, const float* __restrict__ adst,
                            const int* __restrict__ esrc, const int* __restrict__ row_ptr,
                            const int* __restrict__ csr_e,
                            const void* __restrict__ bias, const float* __restrict__ ident,
                            void* __restrict__ out, bf16* __restrict__ outb,
                            const int* __restrict__ flags,
                            int E, int N, int H, int mode) {
    __shared__ float el[4][CAP * 10];   // logits -> exp weights; reused as scratch in mode 2
    __shared__ int   ssrc[4][CAP];
    __shared__ float idn[4][10];
    int wid = threadIdx.x >> 6, lane = threadIdx.x & 63;
    int d = blockIdx.x * 4 + wid;
    bool active = d < N;
    int isf32 = get_isf32(flags);
    int F = H * 32;
    int nj = (F + 255) >> 8;  // 1 (F=256) or 2 (F=320)
    int lo = 0, deg = 0;
    if (active) { lo = row_ptr[d]; deg = row_ptr[d + 1] - lo; }
    bool fast = deg <= CAP;

    // ---- Pass A: logits into LDS ----
    if (active && fast) {
        int EC = 64 / H;              // edges per chunk (8 for H=8, 6 for H=10)
        int h = lane % H, ei = lane / H;
        float ad = adst[(size_t)d * H + h];
        for (int base = 0; base < deg; base += EC) {
            int p = base + ei;
            if (ei < EC && p < deg) {
                int e = csr_e[lo + p];
                int s = (e < E) ? esrc[e] : (e - E);
                float v = asrc[(size_t)s * H + h] + ad;
                v = (v > 0.f) ? v : 0.2f * v;
                el[wid][p * H + h] = v;
                if (h == 0) ssrc[wid][p] = s;
            }
        }
    }
    __syncthreads();
    // ---- Pass M: per-head softmax normalization ----
    if (active && fast && lane < H) {
        float m = -1e30f;
        for (int p = 0; p < deg; ++p) m = fmaxf(m, el[wid][p * H + lane]);
        float den = 0.f;
        for (int p = 0; p < deg; ++p) {
            float t = __expf(el[wid][p * H + lane] - m);
            el[wid][p * H + lane] = t;
            den += t;
        }
        idn[wid][lane] = 1.f / (den + 1e-16f);
    }
    __syncthreads();

    f32x4 acc[2] = {(f32x4){0.f, 0.f, 0.f, 0.f}, (f32x4){0.f, 0.f, 0.f, 0.f}};
    if (active) {
        if (fast) {
#pragma unroll 2
            for (int p = 0; p < deg; ++p) {
                int s = ssrc[wid][p];
                const bf16* hp = hlin + (size_t)s * F;
#pragma unroll
                for (int j = 0; j < 2; ++j) {
                    int f0 = (lane + 64 * j) * 4;
                    if (j < nj && f0 < F) {
                        bf16x4 hv = *(const bf16x4*)(hp + f0);
                        float w = el[wid][p * H + (f0 >> 5)];
#pragma unroll
                        for (int k = 0; k < 4; ++k) acc[j][k] += w * bf2fs(hv[k]);
                    }
                }
            }
#pragma unroll
            for (int j = 0; j < 2; ++j) {
                int f0 = (lane + 64 * j) * 4;
                if (j < nj && f0 < F) {
                    float inv = idn[wid][f0 >> 5];
#pragma unroll
                    for (int k = 0; k < 4; ++k) acc[j][k] *= inv;
                }
            }
        } else {
            // slow path: recompute logits per lane-channel-group (deg > CAP, rare)
            for (int j = 0; j < nj; ++j) {
                int f0 = (lane + 64 * j) * 4;
                if (f0 >= F) continue;
                int hj = f0 >> 5;
                float ad = adst[(size_t)d * H + hj];
                float m = -1e30f;
                for (int p = 0; p < deg; ++p) {
                    int e = csr_e[lo + p];
                    int s = (e < E) ? esrc[e] : (e - E);
                    float v = asrc[(size_t)s * H + hj] + ad;
                    v = (v > 0.f) ? v : 0.2f * v;
                    m = fmaxf(m, v);
                }
                float den = 0.f;
                f32x4 a4 = {0.f, 0.f, 0.f, 0.f};
                for (int p = 0; p < deg; ++p) {
                    int e = csr_e[lo + p];
                    int s = (e < E) ? esrc[e] : (e - E);
                    float v = asrc[(size_t)s * H + hj] + ad;
                    v = (v > 0.f) ? v : 0.2f * v;
                    float t = __expf(v - m);
                    den += t;
                    bf16x4 hv = *(const bf16x4*)(hlin + (size_t)s * F + f0);
                    for (int k = 0; k < 4; ++k) a4[k] += t * bf2fs(hv[k]);
                }
                float inv = 1.f / (den + 1e-16f);
                for (int k = 0; k < 4; ++k) acc[j][k] = a4[k] * inv;
            }
        }
        // ---- epilogue ----
        if (mode == 1) {
            float* o = (float*)out;
            int f0 = lane * 4;  // nj==1 here (F=256)
            f32x4 idv = *(const f32x4*)(ident + (size_t)d * F + f0);
            f32x4 ov;
            bf16x4 ob;
#pragma unroll
            for (int k = 0; k < 4; ++k) {
                float v = acc[0][k] + loadf(bias, f0 + k, isf32);
                v = (v > 0.f) ? v : (__expf(v) - 1.f);  // ELU
                v += idv[k];
                ov[k] = v;
                ob[k] = f2bfs(v);
            }
            *(f32x4*)(o + (size_t)d * F + f0) = ov;
            *(bf16x4*)(outb + (size_t)d * F + f0) = ob;
        } else {
            // stage normalized acc to per-wave LDS scratch (reuse el), then
            // lanes 0..31 sum the 10 heads for their channel.
            float* scratch = &el[wid][0];
#pragma unroll
            for (int j = 0; j < 2; ++j) {
                int f0 = (lane + 64 * j) * 4;
                if (j < nj && f0 < F) {
#pragma unroll
                    for (int k = 0; k < 4; ++k) scratch[f0 + k] = acc[j][k];
                }
            }
            // wave-internal LDS dependency; compiler inserts lgkmcnt wait
            if (lane < 32) {
                float s = 0.f;
                for (int h = 0; h < H; ++h) s += scratch[h * 32 + lane];
                float v = s * (1.f / (float)H) + loadf(bias, lane, isf32)
                        + ident[(size_t)d * 32 + lane];
                if (isf32) ((float*)out)[(size_t)d * 32 + lane] = v;
                else ((bf16*)out)[(size_t)d * 32 + lane] = __float2bfloat16(v);
            }
        }
    }
}

extern "C" void kernel_launch(void* const* d_in, const int* in_sizes, int n_in,
                              void* d_out, int out_size, void* d_ws, size_t ws_size,
                              hipStream_t stream) {
    const int IN = 256, C = 32;
    const int N = in_sizes[0] / IN;
    const int E = in_sizes[1] / 2;
    const int ET = E + N;

    const void* x    = d_in[0];
    const int*  edge = (const int*)d_in[1];
    const void* W1 = d_in[2];
    const void* a1s = d_in[3];
    const void* a1d = d_in[4];
    const void* b1 = d_in[5];
    const void* W2 = d_in[6];
    const void* a2s = d_in[7];
    const void* a2d = d_in[8];
    const void* b2 = d_in[9];
    const void* W3 = d_in[10];
    const void* a3s = d_in[11];
    const void* a3d = d_in[12];
    const void* b3 = d_in[13];
    const void* P1W = d_in[14];
    const void* P1b = d_in[15];
    const void* P3W = d_in[16];
    const void* P3b = d_in[17];

    char* ws = (char*)d_ws;
    size_t off = 0;
    auto alloc = [&](size_t bytes) -> void* {
        void* p = ws + off;
        off = (off + bytes + 255) & ~(size_t)255;
        return p;
    };
    bf16* fxb   = (bf16*)alloc((size_t)N * 256 * 2);    // bf16 input
    bf16* fyb   = (bf16*)alloc((size_t)N * 256 * 2);    // bf16 layer outputs
    bf16* fhb   = (bf16*)alloc((size_t)N * 320 * 2);    // h_lin bf16 (per layer)
    float* fy   = (float*)alloc((size_t)N * 256 * 4);   // f32 layer outputs
    float* fid  = (float*)alloc((size_t)N * 256 * 4);   // identity1 / identity3
    float* fasrc = (float*)alloc((size_t)N * 10 * 4);
    float* fadst = (float*)alloc((size_t)N * 10 * 4);
    bf16* wb1   = (bf16*)alloc((size_t)256 * 256 * 2);
    bf16* wbP1  = (bf16*)alloc((size_t)256 * 256 * 2);
    bf16* wb2   = (bf16*)alloc((size_t)256 * 256 * 2);
    bf16* wb3   = (bf16*)alloc((size_t)320 * 256 * 2);
    bf16* wbP3  = (bf16*)alloc((size_t)32 * 256 * 2);
    int*  isrc  = (int*)alloc((size_t)E * 4);
    int*  idst  = (int*)alloc((size_t)E * 4);
    int*  irow  = (int*)alloc((size_t)(N + 1) * 4);
    int*  icur  = (int*)alloc((size_t)N * 4);
    int*  icsr  = (int*)alloc((size_t)ET * 4);
    int*  flags = (int*)alloc(4 * 4);
    (void)ws_size;

    auto cdiv = [](int a, int b) { return (a + b - 1) / b; };

    // dtype detection (prefix probe, ballot-reduced, one launch)
    int nprobe_x = (N * 256 < 262144) ? N * 256 : 262144;
    int nprobe_e = (2 * E < 65536) ? 2 * E : 65536;
    hipMemsetAsync(flags, 0, 16, stream);
    int bx = cdiv(nprobe_x, 256);
    k_detect<<<bx + cdiv(nprobe_e, 256), 256, 0, stream>>>(
        (const unsigned short*)x, edge, flags, nprobe_x, nprobe_e, bx);

    // normalize inputs (single fused cast launch; counts in 8-elem units)
    int c_x = N * 256 / 8, c_w = 256 * 256 / 8, c_w3 = 320 * 256 / 8, c_p3 = 32 * 256 / 8;
    int ctot = c_x + 3 * c_w + c_w3 + c_p3;
    k_cast_all<<<cdiv(ctot, 256), 256, 0, stream>>>(
        x, fxb, c_x, W1, wb1, c_w, P1W, wbP1, c_w, W2, wb2, c_w,
        W3, wb3, c_w3, P3W, wbP3, c_p3, flags);
    k_norm_e<<<cdiv(E, 256), 256, 0, stream>>>(edge, flags, isrc, idst, E);

    // CSR over dst (edges + self-loops)
    hipMemsetAsync(icur, 0, (size_t)N * 4, stream);
    k_count<<<cdiv(ET, 256), 256, 0, stream>>>(idst, icur, E, N);
    k_scan<<<1, 256, 0, stream>>>(icur, irow, N);
    k_copy_i<<<cdiv(N, 256), 256, 0, stream>>>(irow, icur, N);
    k_fill<<<cdiv(ET, 256), 256, 0, stream>>>(idst, icur, icsr, E, N);

    int gx = cdiv(N, 64);
    int ga = cdiv(N, 4);

    // ---- Layer 1: H=8, F=256 ----
    {
        int H = 8;
        k_gemm_mfma<4, true><<<dim3(gx, 4), 256, 0, stream>>>(fxb, wb1, nullptr, flags, fhb, N, 256, 256);
        k_gemm_mfma<4, false><<<dim3(gx, 4), 256, 0, stream>>>(fxb, wbP1, P1b, flags, fid, N, 256, 256);
        k_node_alpha<<<cdiv(N * H, 256), 256, 0, stream>>>(fhb, a1s, a1d, flags, fasrc, fadst, N, H, C);
        k_fused_agg<<<ga, 256, 0, stream>>>(fhb, fasrc, fadst, isrc, irow, icsr, b1, fid, fy, fyb, flags, E, N, H, 1);
    }
    // ---- Layer 2: H=8, F=256, identity = layer-1 output ----
    {
        int H = 8;
        k_gemm_mfma<4, true><<<dim3(gx, 4), 256, 0, stream>>>(fyb, wb2, nullptr, flags, fhb, N, 256, 256);
        k_node_alpha<<<cdiv(N * H, 256), 256, 0, stream>>>(fhb, a2s, a2d, flags, fasrc, fadst, N, H, C);
        k_fused_agg<<<ga, 256, 0, stream>>>(fhb, fasrc, fadst, isrc, irow, icsr, b2, fy, fy, fyb, flags, E, N, H, 1);
    }
    // ---- Layer 3: H=10, concat=False (head-mean fused) ----
    {
        int H = 10;
        k_gemm_mfma<4, true><<<dim3(gx, 5), 256, 0, stream>>>(fyb, wb3, nullptr, flags, fhb, N, 320, 256);
        k_gemm_mfma<2, false><<<dim3(gx, 1), 256, 0, stream>>>(fyb, wbP3, P3b, flags, fid, N, 32, 256);
        k_node_alpha<<<cdiv(N * H, 256), 256, 0, stream>>>(fhb, a3s, a3d, flags, fasrc, fadst, N, H, C);
        k_fused_agg<<<ga, 256, 0, stream>>>(fhb, fasrc, fadst, isrc, irow, icsr, b3, fid, d_out, nullptr, flags, E, N, H, 2);
    }
}

// Round 7
// 292.758 us; speedup vs baseline: 5.0065x; 1.3141x over previous
//
#include <hip/hip_runtime.h>
#include <hip/hip_bf16.h>

typedef __hip_bfloat16 bf16;
typedef __attribute__((ext_vector_type(8))) short bf16x8;
typedef __attribute__((ext_vector_type(4))) short bf16x4;
typedef __attribute__((ext_vector_type(4))) float f32x4;

// ---------------------------------------------------------------------------
// 3-layer GAT forward. Dtype-adaptive (observed world: floats=bf16, edges=i32).
// flags[0]=1 if NaN/Inf ushort pattern in x-prefix (=> x is f32)
// flags[1]=1 if any odd 32-bit word of edge prefix nonzero (=> edges i32)
// flags[2]=1 if any even-index ushort of x-prefix nonzero
// isf32 = flags[0] || !flags[2]
// ---------------------------------------------------------------------------

static __device__ __forceinline__ float bf2f(bf16 v) { return __bfloat162float(v); }
static __device__ __forceinline__ float bf2fs(short v) {
    unsigned int u = ((unsigned int)(unsigned short)v) << 16;
    return __builtin_bit_cast(float, u);
}
static __device__ __forceinline__ short f2bfs(float f) {
    bf16 b = __float2bfloat16(f);
    return __builtin_bit_cast(short, b);
}
static __device__ __forceinline__ float loadf(const void* p, size_t i, int isf32) {
    return isf32 ? ((const float*)p)[i] : bf2f(((const bf16*)p)[i]);
}
static __device__ __forceinline__ int get_isf32(const int* flags) {
    return (flags[0] | (flags[2] == 0)) ? 1 : 0;
}

// detection: tiny probe, LDS block aggregation, <=3 atomics per block.
// blocks [0,bx) probe x; blocks [bx,grid) probe edges.
__global__ void k_detect(const unsigned short* __restrict__ xu, const int* __restrict__ ew,
                         int* __restrict__ flags, int nx, int ne2, int bx) {
    __shared__ int lf[3];
    if (threadIdx.x < 3) lf[threadIdx.x] = 0;
    __syncthreads();
    if ((int)blockIdx.x < bx) {
        for (int i = blockIdx.x * 256 + threadIdx.x; i < nx; i += bx * 256) {
            unsigned short v = xu[i];
            if ((v & 0x7F80u) == 0x7F80u) lf[0] = 1;
            if (((i & 1) == 0) && v != 0) lf[2] = 1;
        }
    } else {
        int nb = gridDim.x - bx;
        for (int i = (blockIdx.x - bx) * 256 + threadIdx.x; i < ne2; i += nb * 256) {
            if ((i & 1) && ew[i] != 0) lf[1] = 1;
        }
    }
    __syncthreads();
    if (threadIdx.x == 0) {
        if (lf[0]) atomicOr(&flags[0], 1);
        if (lf[1]) atomicOr(&flags[1], 1);
        if (lf[2]) atomicOr(&flags[2], 1);
    }
}

// 8-elem vectorized adaptive cast
static __device__ __forceinline__ void cast8(const void* src, bf16* dst, int i8, int isf32) {
    if (isf32) {
        f32x4 a = ((const f32x4*)src)[2 * i8];
        f32x4 b = ((const f32x4*)src)[2 * i8 + 1];
        bf16x8 o;
        o[0] = f2bfs(a[0]); o[1] = f2bfs(a[1]); o[2] = f2bfs(a[2]); o[3] = f2bfs(a[3]);
        o[4] = f2bfs(b[0]); o[5] = f2bfs(b[1]); o[6] = f2bfs(b[2]); o[7] = f2bfs(b[3]);
        ((bf16x8*)dst)[i8] = o;
    } else {
        ((bf16x8*)dst)[i8] = ((const bf16x8*)src)[i8];
    }
}

// all input casts in one launch (counts are in 8-elem units)
__global__ void k_cast_all(const void* s0, bf16* d0, int c0,
                           const void* s1, bf16* d1, int c1,
                           const void* s2, bf16* d2, int c2,
                           const void* s3, bf16* d3, int c3,
                           const void* s4, bf16* d4, int c4,
                           const void* s5, bf16* d5, int c5,
                           const int* __restrict__ flags) {
    int t = blockIdx.x * blockDim.x + threadIdx.x;
    int isf32 = get_isf32(flags);
    if (t < c0) { cast8(s0, d0, t, isf32); return; } t -= c0;
    if (t < c1) { cast8(s1, d1, t, isf32); return; } t -= c1;
    if (t < c2) { cast8(s2, d2, t, isf32); return; } t -= c2;
    if (t < c3) { cast8(s3, d3, t, isf32); return; } t -= c3;
    if (t < c4) { cast8(s4, d4, t, isf32); return; } t -= c4;
    if (t < c5) { cast8(s5, d5, t, isf32); }
}

// normalize edges to int32 src/dst + in-degree count (fused)
__global__ void k_norm_count(const int* __restrict__ w, const int* __restrict__ flags,
                             int* __restrict__ s, int* __restrict__ d,
                             int* __restrict__ cnt, int E) {
    int e = blockIdx.x * blockDim.x + threadIdx.x;
    if (e >= E) return;
    int sv, dv;
    if (flags[1] == 0) {  // int64
        sv = w[2 * (size_t)e];
        dv = w[2 * (size_t)E + 2 * (size_t)e];
    } else {              // int32
        sv = w[e];
        dv = w[(size_t)E + e];
    }
    s[e] = sv;
    d[e] = dv;
    atomicAdd(&cnt[dv], 1);
}

// single-block scan: row_ptr[i+1] = sum_{j<=i}(cnt[j]+1)  (+1 = self-loop),
// and cursor[i] = row_ptr[i] (exclusive prefix; overwrites cnt buffer).
__global__ void k_scan(int* __restrict__ cnt, int* __restrict__ row_ptr, int N) {
    __shared__ int tmp[256];
    __shared__ int carry_s;
    if (threadIdx.x == 0) { carry_s = 0; row_ptr[0] = 0; }
    __syncthreads();
    for (int base = 0; base < N; base += 256) {
        int i = base + (int)threadIdx.x;
        int myc = (i < N) ? cnt[i] + 1 : 0;
        tmp[threadIdx.x] = myc;
        __syncthreads();
        for (int off = 1; off < 256; off <<= 1) {
            int t = (threadIdx.x >= (unsigned)off) ? tmp[threadIdx.x - off] : 0;
            __syncthreads();
            tmp[threadIdx.x] += t;
            __syncthreads();
        }
        int c = carry_s;
        if (i < N) {
            row_ptr[i + 1] = c + tmp[threadIdx.x];
            cnt[i] = c + tmp[threadIdx.x] - myc;  // cursor = exclusive prefix
        }
        __syncthreads();
        if (threadIdx.x == 0) carry_s = c + tmp[255];
        __syncthreads();
    }
}

// fill CSR: edges via atomic cursor; self-loop of node d at row_ptr[d+1]-1.
__global__ void k_fill(const int* __restrict__ edst, int* __restrict__ cursor,
                       const int* __restrict__ row_ptr, int* __restrict__ csr_e,
                       int E, int N) {
    int e = blockIdx.x * blockDim.x + threadIdx.x;
    if (e < E) {
        int d = edst[e];
        int pos = atomicAdd(&cursor[d], 1);
        csr_e[pos] = e;
    } else if (e < E + N) {
        int d = e - E;
        csr_e[row_ptr[d + 1] - 1] = e;
    }
}

// ---------------------------------------------------------------------------
// MFMA GEMM core loop (shared). C[M,Fo] = A[M,K](bf16) * W[Fo,K](bf16)^T.
// ---------------------------------------------------------------------------
template<int NT, bool OB>
__global__ void k_gemm_mfma(const bf16* __restrict__ A, const bf16* __restrict__ W,
                            const void* __restrict__ bias, const int* __restrict__ flags,
                            void* __restrict__ Cp, int M, int Fo, int K) {
    int wid = threadIdx.x >> 6;
    int lane = threadIdx.x & 63;
    int mrow = blockIdx.x * 64 + wid * 16;
    if (mrow >= M) return;
    int ncol = blockIdx.y * (NT * 16);
    int r = lane & 15, g = lane >> 4;

    f32x4 acc[NT];
#pragma unroll
    for (int t = 0; t < NT; ++t) acc[t] = (f32x4){0.f, 0.f, 0.f, 0.f};

    const bf16* arow = A + (size_t)(mrow + r) * K + g * 8;
    const bf16* wbase = W + (size_t)(ncol + r) * K + g * 8;
    for (int k0 = 0; k0 < K; k0 += 32) {
        bf16x8 af = *(const bf16x8*)(arow + k0);
#pragma unroll
        for (int t = 0; t < NT; ++t) {
            bf16x8 bfr = *(const bf16x8*)(wbase + (size_t)t * 16 * K + k0);
            acc[t] = __builtin_amdgcn_mfma_f32_16x16x32_bf16(af, bfr, acc[t], 0, 0, 0);
        }
    }
    int isf32 = flags ? get_isf32(flags) : 0;
#pragma unroll
    for (int t = 0; t < NT; ++t) {
        int n = ncol + t * 16 + r;
        float bv = bias ? loadf(bias, n, isf32) : 0.f;
#pragma unroll
        for (int j = 0; j < 4; ++j) {
            int m = mrow + 4 * g + j;
            float v = acc[t][j] + bv;
            if (OB) ((bf16*)Cp)[(size_t)m * Fo + n] = __float2bfloat16(v);
            else    ((float*)Cp)[(size_t)m * Fo + n] = v;
        }
    }
}

// Split-output GEMM: cols [0,S0) -> out0 (bf16, ld0); cols [S0, S0+n1) -> out1
// (f32, ld1, +bias1). Cols >= S0+n1 are padding, discarded.
template<int NT>
__global__ void k_gemm_split(const bf16* __restrict__ A, const bf16* __restrict__ W,
                             const void* __restrict__ bias1, const int* __restrict__ flags,
                             bf16* __restrict__ out0, int S0, int ld0,
                             float* __restrict__ out1, int ld1, int n1,
                             int M, int Fo, int K) {
    int wid = threadIdx.x >> 6;
    int lane = threadIdx.x & 63;
    int mrow = blockIdx.x * 64 + wid * 16;
    if (mrow >= M) return;
    int ncol = blockIdx.y * (NT * 16);
    int r = lane & 15, g = lane >> 4;

    f32x4 acc[NT];
#pragma unroll
    for (int t = 0; t < NT; ++t) acc[t] = (f32x4){0.f, 0.f, 0.f, 0.f};

    const bf16* arow = A + (size_t)(mrow + r) * K + g * 8;
    const bf16* wbase = W + (size_t)(ncol + r) * K + g * 8;
    for (int k0 = 0; k0 < K; k0 += 32) {
        bf16x8 af = *(const bf16x8*)(arow + k0);
#pragma unroll
        for (int t = 0; t < NT; ++t) {
            bf16x8 bfr = *(const bf16x8*)(wbase + (size_t)t * 16 * K + k0);
            acc[t] = __builtin_amdgcn_mfma_f32_16x16x32_bf16(af, bfr, acc[t], 0, 0, 0);
        }
    }
    int isf32 = get_isf32(flags);
#pragma unroll
    for (int t = 0; t < NT; ++t) {
        int n = ncol + t * 16 + r;
        bool is0 = n < S0;
        int jc = n - S0;
        float bv = (!is0 && jc < n1 && bias1) ? loadf(bias1, jc, isf32) : 0.f;
#pragma unroll
        for (int j = 0; j < 4; ++j) {
            int m = mrow + 4 * g + j;
            float v = acc[t][j] + bv;
            if (is0) out0[(size_t)m * ld0 + n] = __float2bfloat16(v);
            else if (jc < n1) out1[(size_t)m * ld1 + jc] = v;
        }
    }
}

// per-(node,head) attention logits (h in bf16, vectorized loads)
__global__ void k_node_alpha(const bf16* __restrict__ h, const void* __restrict__ a_s,
                             const void* __restrict__ a_d, const int* __restrict__ flags,
                             float* __restrict__ asrc, float* __restrict__ adst,
                             int N, int H, int C) {
    int i = blockIdx.x * blockDim.x + threadIdx.x;
    if (i >= N * H) return;
    int isf32 = get_isf32(flags);
    int n = i / H, hh = i % H;
    const bf16x8* hp8 = (const bf16x8*)(h + (size_t)n * H * C + (size_t)hh * C);
    float s1 = 0.f, s2 = 0.f;
#pragma unroll
    for (int c8 = 0; c8 < 4; ++c8) {
        bf16x8 hv = hp8[c8];
#pragma unroll
        for (int k = 0; k < 8; ++k) {
            float v = bf2fs(hv[k]);
            int c = c8 * 8 + k;
            s1 += v * loadf(a_s, hh * C + c, isf32);
            s2 += v * loadf(a_d, hh * C + c, isf32);
        }
    }
    asrc[i] = s1;
    adst[i] = s2;
}

// ---------------------------------------------------------------------------
// Fused per-dst-node softmax + aggregation. One wave per dst node, 4 waves/blk.
// mode 1 (F=256, H=8) fast path: paired edges — lanes 0-31 edge p, lanes 32-63
// edge p+1, 16B bf16x8 per lane, shfl_xor(32) combine, float4 epilogue.
// mode 2 (F=320, H=10): 4-channel granules; head-mean via per-wave LDS scratch.
// Degree > CAP: slow recompute path.
// ---------------------------------------------------------------------------
#define CAP 96
__global__ void k_fused_agg(const bf16* __restrict__ hlin,
                            const float* __restrict__ asrc, const float* __restrict__ adst,
                            const int* __restrict__ esrc, const int* __restrict__ row_ptr,
                            const int* __restrict__ csr_e,
                            const void* __restrict__ bias, const float* __restrict__ ident,
                            void* __restrict__ out, bf16* __restrict__ outb,
                            const int* __restrict__ flags,
                            int E, int N, int H, int mode) {
    __shared__ float el[4][CAP * 10];   // logits -> exp weights; scratch in mode 2
    __shared__ int   ssrc[4][CAP];
    __shared__ float idn[4][10];
    int wid = threadIdx.x >> 6, lane = threadIdx.x & 63;
    int d = blockIdx.x * 4 + wid;
    bool active = d < N;
    int isf32 = get_isf32(flags);
    int F = H * 32;
    int nj = (F + 255) >> 8;  // 1 (F=256) or 2 (F=320)
    int lo = 0, deg = 0;
    if (active) { lo = row_ptr[d]; deg = row_ptr[d + 1] - lo; }
    bool fast = deg <= CAP;

    // ---- Pass A: logits into LDS ----
    if (active && fast) {
        int EC = 64 / H;
        int h = lane % H, ei = lane / H;
        float ad = adst[(size_t)d * H + h];
        for (int base = 0; base < deg; base += EC) {
            int p = base + ei;
            if (ei < EC && p < deg) {
                int e = csr_e[lo + p];
                int s = (e < E) ? esrc[e] : (e - E);
                float v = asrc[(size_t)s * H + h] + ad;
                v = (v > 0.f) ? v : 0.2f * v;
                el[wid][p * H + h] = v;
                if (h == 0) ssrc[wid][p] = s;
            }
        }
    }
    __syncthreads();
    // ---- Pass M: per-head softmax normalization ----
    if (active && fast && lane < H) {
        float m = -1e30f;
        for (int p = 0; p < deg; ++p) m = fmaxf(m, el[wid][p * H + lane]);
        float den = 0.f;
        for (int p = 0; p < deg; ++p) {
            float t = __expf(el[wid][p * H + lane] - m);
            el[wid][p * H + lane] = t;
            den += t;
        }
        idn[wid][lane] = 1.f / (den + 1e-16f);
    }
    __syncthreads();
    if (!active) return;

    if (mode == 1 && fast) {
        // ---- paired-edge gather: F=256, H=8 ----
        int half = lane >> 5, g = lane & 31;
        f32x4 a0 = {0.f, 0.f, 0.f, 0.f}, a1 = {0.f, 0.f, 0.f, 0.f};
        for (int p = half; p < deg; p += 2) {
            int s = ssrc[wid][p];
            bf16x8 hv = *(const bf16x8*)(hlin + (size_t)s * 256 + g * 8);
            float w = el[wid][p * 8 + (g >> 2)];
#pragma unroll
            for (int k = 0; k < 4; ++k) {
                a0[k] += w * bf2fs(hv[k]);
                a1[k] += w * bf2fs(hv[4 + k]);
            }
        }
#pragma unroll
        for (int k = 0; k < 4; ++k) {
            a0[k] += __shfl_xor(a0[k], 32);
            a1[k] += __shfl_xor(a1[k], 32);
        }
        if (lane < 32) {
            float inv = idn[wid][g >> 2];
            int f0 = g * 8;
            f32x4 id0 = *(const f32x4*)(ident + (size_t)d * 256 + f0);
            f32x4 id1 = *(const f32x4*)(ident + (size_t)d * 256 + f0 + 4);
            f32x4 o0, o1;
            bf16x8 ob;
#pragma unroll
            for (int k = 0; k < 4; ++k) {
                float v = a0[k] * inv + loadf(bias, f0 + k, isf32);
                v = (v > 0.f) ? v : (__expf(v) - 1.f);
                v += id0[k];
                o0[k] = v; ob[k] = f2bfs(v);
            }
#pragma unroll
            for (int k = 0; k < 4; ++k) {
                float v = a1[k] * inv + loadf(bias, f0 + 4 + k, isf32);
                v = (v > 0.f) ? v : (__expf(v) - 1.f);
                v += id1[k];
                o1[k] = v; ob[4 + k] = f2bfs(v);
            }
            float* o = (float*)out;
            *(f32x4*)(o + (size_t)d * 256 + f0) = o0;
            *(f32x4*)(o + (size_t)d * 256 + f0 + 4) = o1;
            *(bf16x8*)(outb + (size_t)d * 256 + f0) = ob;
        }
        return;
    }

    // ---- generic path (mode 2 fast, or slow path any mode) ----
    f32x4 acc[2] = {(f32x4){0.f, 0.f, 0.f, 0.f}, (f32x4){0.f, 0.f, 0.f, 0.f}};
    if (fast) {
#pragma unroll 2
        for (int p = 0; p < deg; ++p) {
            int s = ssrc[wid][p];
            const bf16* hp = hlin + (size_t)s * F;
#pragma unroll
            for (int j = 0; j < 2; ++j) {
                int f0 = (lane + 64 * j) * 4;
                if (j < nj && f0 < F) {
                    bf16x4 hv = *(const bf16x4*)(hp + f0);
                    float w = el[wid][p * H + (f0 >> 5)];
#pragma unroll
                    for (int k = 0; k < 4; ++k) acc[j][k] += w * bf2fs(hv[k]);
                }
            }
        }
#pragma unroll
        for (int j = 0; j < 2; ++j) {
            int f0 = (lane + 64 * j) * 4;
            if (j < nj && f0 < F) {
                float inv = idn[wid][f0 >> 5];
#pragma unroll
                for (int k = 0; k < 4; ++k) acc[j][k] *= inv;
            }
        }
    } else {
        for (int j = 0; j < nj; ++j) {
            int f0 = (lane + 64 * j) * 4;
            if (f0 >= F) continue;
            int hj = f0 >> 5;
            float ad = adst[(size_t)d * H + hj];
            float m = -1e30f;
            for (int p = 0; p < deg; ++p) {
                int e = csr_e[lo + p];
                int s = (e < E) ? esrc[e] : (e - E);
                float v = asrc[(size_t)s * H + hj] + ad;
                v = (v > 0.f) ? v : 0.2f * v;
                m = fmaxf(m, v);
            }
            float den = 0.f;
            f32x4 a4 = {0.f, 0.f, 0.f, 0.f};
            for (int p = 0; p < deg; ++p) {
                int e = csr_e[lo + p];
                int s = (e < E) ? esrc[e] : (e - E);
                float v = asrc[(size_t)s * H + hj] + ad;
                v = (v > 0.f) ? v : 0.2f * v;
                float t = __expf(v - m);
                den += t;
                bf16x4 hv = *(const bf16x4*)(hlin + (size_t)s * F + f0);
                for (int k = 0; k < 4; ++k) a4[k] += t * bf2fs(hv[k]);
            }
            float inv = 1.f / (den + 1e-16f);
            for (int k = 0; k < 4; ++k) acc[j][k] = a4[k] * inv;
        }
    }
    // ---- epilogues for generic path ----
    if (mode == 1) {
        float* o = (float*)out;
        int f0 = lane * 4;
        f32x4 idv = *(const f32x4*)(ident + (size_t)d * F + f0);
        f32x4 ov;
        bf16x4 ob;
#pragma unroll
        for (int k = 0; k < 4; ++k) {
            float v = acc[0][k] + loadf(bias, f0 + k, isf32);
            v = (v > 0.f) ? v : (__expf(v) - 1.f);
            v += idv[k];
            ov[k] = v;
            ob[k] = f2bfs(v);
        }
        *(f32x4*)(o + (size_t)d * F + f0) = ov;
        *(bf16x4*)(outb + (size_t)d * F + f0) = ob;
    } else {
        float* scratch = &el[wid][0];
#pragma unroll
        for (int j = 0; j < 2; ++j) {
            int f0 = (lane + 64 * j) * 4;
            if (j < nj && f0 < F) {
#pragma unroll
                for (int k = 0; k < 4; ++k) scratch[f0 + k] = acc[j][k];
            }
        }
        if (lane < 32) {
            float s = 0.f;
            for (int h = 0; h < H; ++h) s += scratch[h * 32 + lane];
            float v = s * (1.f / (float)H) + loadf(bias, lane, isf32)
                    + ident[(size_t)d * 32 + lane];
            if (isf32) ((float*)out)[(size_t)d * 32 + lane] = v;
            else ((bf16*)out)[(size_t)d * 32 + lane] = __float2bfloat16(v);
        }
    }
}

extern "C" void kernel_launch(void* const* d_in, const int* in_sizes, int n_in,
                              void* d_out, int out_size, void* d_ws, size_t ws_size,
                              hipStream_t stream) {
    const int IN = 256, C = 32;
    const int N = in_sizes[0] / IN;
    const int E = in_sizes[1] / 2;
    const int ET = E + N;

    const void* x    = d_in[0];
    const int*  edge = (const int*)d_in[1];
    const void* W1 = d_in[2];
    const void* a1s = d_in[3];
    const void* a1d = d_in[4];
    const void* b1 = d_in[5];
    const void* W2 = d_in[6];
    const void* a2s = d_in[7];
    const void* a2d = d_in[8];
    const void* b2 = d_in[9];
    const void* W3 = d_in[10];
    const void* a3s = d_in[11];
    const void* a3d = d_in[12];
    const void* b3 = d_in[13];
    const void* P1W = d_in[14];
    const void* P1b = d_in[15];
    const void* P3W = d_in[16];
    const void* P3b = d_in[17];

    char* ws = (char*)d_ws;
    size_t off = 0;
    auto alloc = [&](size_t bytes) -> void* {
        void* p = ws + off;
        off = (off + bytes + 255) & ~(size_t)255;
        return p;
    };
    bf16* fxb   = (bf16*)alloc((size_t)N * 256 * 2);    // bf16 input
    bf16* fyb   = (bf16*)alloc((size_t)N * 256 * 2);    // bf16 layer outputs
    bf16* fhb   = (bf16*)alloc((size_t)N * 320 * 2);    // h_lin bf16 (per layer)
    float* fy   = (float*)alloc((size_t)N * 256 * 4);   // f32 layer outputs
    float* fid  = (float*)alloc((size_t)N * 256 * 4);   // identity1 / identity3
    float* fasrc = (float*)alloc((size_t)N * 10 * 4);
    float* fadst = (float*)alloc((size_t)N * 10 * 4);
    bf16* wc1   = (bf16*)alloc((size_t)512 * 256 * 2);  // [W1; P1W]
    bf16* wb2   = (bf16*)alloc((size_t)256 * 256 * 2);
    bf16* wc3   = (bf16*)alloc((size_t)384 * 256 * 2);  // [W3; P3W; 32 pad rows]
    int*  isrc  = (int*)alloc((size_t)E * 4);
    int*  idst  = (int*)alloc((size_t)E * 4);
    int*  irow  = (int*)alloc((size_t)(N + 1) * 4);
    int*  icur  = (int*)alloc((size_t)N * 4);
    int*  icsr  = (int*)alloc((size_t)ET * 4);
    int*  flags = (int*)alloc(4 * 4);
    (void)ws_size;

    auto cdiv = [](int a, int b) { return (a + b - 1) / b; };

    // dtype detection (tiny prefix probe, block-aggregated)
    int nprobe_x = (N * 256 < 16384) ? N * 256 : 16384;
    int nprobe_e = (2 * E < 8192) ? 2 * E : 8192;
    hipMemsetAsync(flags, 0, 16, stream);
    int bx = cdiv(nprobe_x, 256) < 16 ? cdiv(nprobe_x, 256) : 16;
    int be = cdiv(nprobe_e, 256) < 8 ? cdiv(nprobe_e, 256) : 8;
    k_detect<<<bx + be, 256, 0, stream>>>(
        (const unsigned short*)x, edge, flags, nprobe_x, nprobe_e, bx);

    // normalize inputs (single fused cast launch; counts in 8-elem units)
    int c_x = N * 256 / 8, c_w = 256 * 256 / 8, c_w3 = 320 * 256 / 8, c_p3 = 32 * 256 / 8;
    int ctot = c_x + 3 * c_w + c_w3 + c_p3;
    k_cast_all<<<cdiv(ctot, 256), 256, 0, stream>>>(
        x, fxb, c_x,
        W1, wc1, c_w,
        P1W, wc1 + (size_t)256 * 256, c_w,
        W2, wb2, c_w,
        W3, wc3, c_w3,
        P3W, wc3 + (size_t)320 * 256, c_p3,
        flags);

    // CSR over dst (edges + self-loops)
    hipMemsetAsync(icur, 0, (size_t)N * 4, stream);
    k_norm_count<<<cdiv(E, 256), 256, 0, stream>>>(edge, flags, isrc, idst, icur, E);
    k_scan<<<1, 256, 0, stream>>>(icur, irow, N);
    k_fill<<<cdiv(ET, 256), 256, 0, stream>>>(idst, icur, irow, icsr, E, N);

    int gx = cdiv(N, 64);
    int ga = cdiv(N, 4);

    // ---- Layer 1: H=8, F=256; combined [W1;P1W] GEMM ----
    {
        int H = 8;
        k_gemm_split<4><<<dim3(gx, 8), 256, 0, stream>>>(
            fxb, wc1, P1b, flags, fhb, 256, 256, fid, 256, 256, N, 512, 256);
        k_node_alpha<<<cdiv(N * H, 256), 256, 0, stream>>>(fhb, a1s, a1d, flags, fasrc, fadst, N, H, C);
        k_fused_agg<<<ga, 256, 0, stream>>>(fhb, fasrc, fadst, isrc, irow, icsr, b1, fid, fy, fyb, flags, E, N, H, 1);
    }
    // ---- Layer 2: H=8, F=256, identity = layer-1 output ----
    {
        int H = 8;
        k_gemm_mfma<4, true><<<dim3(gx, 4), 256, 0, stream>>>(fyb, wb2, nullptr, flags, fhb, N, 256, 256);
        k_node_alpha<<<cdiv(N * H, 256), 256, 0, stream>>>(fhb, a2s, a2d, flags, fasrc, fadst, N, H, C);
        k_fused_agg<<<ga, 256, 0, stream>>>(fhb, fasrc, fadst, isrc, irow, icsr, b2, fy, fy, fyb, flags, E, N, H, 1);
    }
    // ---- Layer 3: H=10, concat=False; combined [W3;P3W;pad] GEMM ----
    {
        int H = 10;
        k_gemm_split<4><<<dim3(gx, 6), 256, 0, stream>>>(
            fyb, wc3, P3b, flags, fhb, 320, 320, fid, 32, 32, N, 384, 256);
        k_node_alpha<<<cdiv(N * H, 256), 256, 0, stream>>>(fhb, a3s, a3d, flags, fasrc, fadst, N, H, C);
        k_fused_agg<<<ga, 256, 0, stream>>>(fhb, fasrc, fadst, isrc, irow, icsr, b3, fid, d_out, nullptr, flags, E, N, H, 2);
    }
}

// Round 8
// 225.542 us; speedup vs baseline: 6.4985x; 1.2980x over previous
//
#include <hip/hip_runtime.h>
#include <hip/hip_bf16.h>

typedef __hip_bfloat16 bf16;
typedef __attribute__((ext_vector_type(8))) short bf16x8;
typedef __attribute__((ext_vector_type(4))) short bf16x4;
typedef __attribute__((ext_vector_type(4))) float f32x4;

// ---------------------------------------------------------------------------
// 3-layer GAT forward. Dtype-adaptive (observed world: floats=bf16, edges=i32).
// flags[0]=1 if NaN/Inf ushort pattern in x-prefix (=> x is f32)
// flags[1]=1 if any odd 32-bit word of edge prefix nonzero (=> edges i32)
// flags[2]=1 if any even-index ushort of x-prefix nonzero
// isf32 = flags[0] || !flags[2]
// ---------------------------------------------------------------------------

static __device__ __forceinline__ float bf2f(bf16 v) { return __bfloat162float(v); }
static __device__ __forceinline__ float bf2fs(short v) {
    unsigned int u = ((unsigned int)(unsigned short)v) << 16;
    return __builtin_bit_cast(float, u);
}
static __device__ __forceinline__ short f2bfs(float f) {
    bf16 b = __float2bfloat16(f);
    return __builtin_bit_cast(short, b);
}
static __device__ __forceinline__ float loadf(const void* p, size_t i, int isf32) {
    return isf32 ? ((const float*)p)[i] : bf2f(((const bf16*)p)[i]);
}
static __device__ __forceinline__ int get_isf32(const int* flags) {
    return (flags[0] | (flags[2] == 0)) ? 1 : 0;
}

// detection: tiny probe, LDS block aggregation, <=3 atomics per block.
__global__ void k_detect(const unsigned short* __restrict__ xu, const int* __restrict__ ew,
                         int* __restrict__ flags, int nx, int ne2, int bx) {
    __shared__ int lf[3];
    if (threadIdx.x < 3) lf[threadIdx.x] = 0;
    __syncthreads();
    if ((int)blockIdx.x < bx) {
        for (int i = blockIdx.x * 256 + threadIdx.x; i < nx; i += bx * 256) {
            unsigned short v = xu[i];
            if ((v & 0x7F80u) == 0x7F80u) lf[0] = 1;
            if (((i & 1) == 0) && v != 0) lf[2] = 1;
        }
    } else {
        int nb = gridDim.x - bx;
        for (int i = (blockIdx.x - bx) * 256 + threadIdx.x; i < ne2; i += nb * 256) {
            if ((i & 1) && ew[i] != 0) lf[1] = 1;
        }
    }
    __syncthreads();
    if (threadIdx.x == 0) {
        if (lf[0]) atomicOr(&flags[0], 1);
        if (lf[1]) atomicOr(&flags[1], 1);
        if (lf[2]) atomicOr(&flags[2], 1);
    }
}

// 8-elem vectorized adaptive cast
static __device__ __forceinline__ void cast8(const void* src, bf16* dst, int i8, int isf32) {
    if (isf32) {
        f32x4 a = ((const f32x4*)src)[2 * i8];
        f32x4 b = ((const f32x4*)src)[2 * i8 + 1];
        bf16x8 o;
        o[0] = f2bfs(a[0]); o[1] = f2bfs(a[1]); o[2] = f2bfs(a[2]); o[3] = f2bfs(a[3]);
        o[4] = f2bfs(b[0]); o[5] = f2bfs(b[1]); o[6] = f2bfs(b[2]); o[7] = f2bfs(b[3]);
        ((bf16x8*)dst)[i8] = o;
    } else {
        ((bf16x8*)dst)[i8] = ((const bf16x8*)src)[i8];
    }
}

// all input casts in one launch (counts are in 8-elem units)
__global__ void k_cast_all(const void* s0, bf16* d0, int c0,
                           const void* s1, bf16* d1, int c1,
                           const void* s2, bf16* d2, int c2,
                           const void* s3, bf16* d3, int c3,
                           const void* s4, bf16* d4, int c4,
                           const void* s5, bf16* d5, int c5,
                           const int* __restrict__ flags) {
    int t = blockIdx.x * blockDim.x + threadIdx.x;
    int isf32 = get_isf32(flags);
    if (t < c0) { cast8(s0, d0, t, isf32); return; } t -= c0;
    if (t < c1) { cast8(s1, d1, t, isf32); return; } t -= c1;
    if (t < c2) { cast8(s2, d2, t, isf32); return; } t -= c2;
    if (t < c3) { cast8(s3, d3, t, isf32); return; } t -= c3;
    if (t < c4) { cast8(s4, d4, t, isf32); return; } t -= c4;
    if (t < c5) { cast8(s5, d5, t, isf32); }
}

// normalize edges to int32 src/dst + in-degree count (fused)
__global__ void k_norm_count(const int* __restrict__ w, const int* __restrict__ flags,
                             int* __restrict__ s, int* __restrict__ d,
                             int* __restrict__ cnt, int E) {
    int e = blockIdx.x * blockDim.x + threadIdx.x;
    if (e >= E) return;
    int sv, dv;
    if (flags[1] == 0) {  // int64
        sv = w[2 * (size_t)e];
        dv = w[2 * (size_t)E + 2 * (size_t)e];
    } else {              // int32
        sv = w[e];
        dv = w[(size_t)E + e];
    }
    s[e] = sv;
    d[e] = dv;
    atomicAdd(&cnt[dv], 1);
}

// single-block 1024-thread scan: row_ptr[i+1] = sum_{j<=i}(cnt[j]+1),
// cursor[i] (= cnt, overwritten) = exclusive prefix.
__global__ void k_scan(int* __restrict__ cnt, int* __restrict__ row_ptr, int N) {
    __shared__ int tmp[1024];
    __shared__ int carry_s;
    if (threadIdx.x == 0) { carry_s = 0; row_ptr[0] = 0; }
    __syncthreads();
    for (int base = 0; base < N; base += 1024) {
        int i = base + (int)threadIdx.x;
        int myc = (i < N) ? cnt[i] + 1 : 0;
        tmp[threadIdx.x] = myc;
        __syncthreads();
        for (int off = 1; off < 1024; off <<= 1) {
            int t = (threadIdx.x >= (unsigned)off) ? tmp[threadIdx.x - off] : 0;
            __syncthreads();
            tmp[threadIdx.x] += t;
            __syncthreads();
        }
        int c = carry_s;
        if (i < N) {
            row_ptr[i + 1] = c + tmp[threadIdx.x];
            cnt[i] = c + tmp[threadIdx.x] - myc;
        }
        __syncthreads();
        if (threadIdx.x == 0) carry_s = c + tmp[1023];
        __syncthreads();
    }
}

// fill CSR: edges via atomic cursor; self-loop of node d at row_ptr[d+1]-1.
__global__ void k_fill(const int* __restrict__ edst, int* __restrict__ cursor,
                       const int* __restrict__ row_ptr, int* __restrict__ csr_e,
                       int E, int N) {
    int e = blockIdx.x * blockDim.x + threadIdx.x;
    if (e < E) {
        int d = edst[e];
        int pos = atomicAdd(&cursor[d], 1);
        csr_e[pos] = e;
    } else if (e < E + N) {
        int d = e - E;
        csr_e[row_ptr[d + 1] - 1] = e;
    }
}

// ---------------------------------------------------------------------------
// Unified MFMA GEMM, split output + fused attention-logit epilogue.
// C[M,Fo] = A[M,K](bf16) * W[Fo,K](bf16)^T.
//   cols [0,S0)        -> out0 (bf16, ld0)  [the attention h part]
//   cols [S0,S0+n1)    -> out1 (f32, ld1, +bias1)
//   cols >= S0+n1      -> discarded (padding)
// If aS != nullptr and the block's cols lie in [0,S0): also compute
//   asrc[m,h] = sum_c h[m,h,c]*aS[h,c], adst likewise. Requires NT==4
//   (64 cols = exactly 2 whole heads of 32 channels).
// grid = (ceil(M/64), Fo/(NT*16)), block = 256 (4 waves), M % 16 == 0.
// D-frag layout (verified m89): col = lane&15 (+16t), row = 4*(lane>>4)+j.
// ---------------------------------------------------------------------------
template<int NT>
__global__ void k_gemm_split(const bf16* __restrict__ A, const bf16* __restrict__ W,
                             const void* __restrict__ bias1, const int* __restrict__ flags,
                             bf16* __restrict__ out0, int S0, int ld0,
                             float* __restrict__ out1, int ld1, int n1,
                             int M, int Fo, int K,
                             const void* __restrict__ aS, const void* __restrict__ aD,
                             float* __restrict__ asrc, float* __restrict__ adst, int H) {
    int wid = threadIdx.x >> 6;
    int lane = threadIdx.x & 63;
    int mrow = blockIdx.x * 64 + wid * 16;
    if (mrow >= M) return;
    int ncol = blockIdx.y * (NT * 16);
    int r = lane & 15, g = lane >> 4;

    f32x4 acc[NT];
#pragma unroll
    for (int t = 0; t < NT; ++t) acc[t] = (f32x4){0.f, 0.f, 0.f, 0.f};

    const bf16* arow = A + (size_t)(mrow + r) * K + g * 8;
    const bf16* wbase = W + (size_t)(ncol + r) * K + g * 8;
    for (int k0 = 0; k0 < K; k0 += 32) {
        bf16x8 af = *(const bf16x8*)(arow + k0);
#pragma unroll
        for (int t = 0; t < NT; ++t) {
            bf16x8 bfr = *(const bf16x8*)(wbase + (size_t)t * 16 * K + k0);
            acc[t] = __builtin_amdgcn_mfma_f32_16x16x32_bf16(af, bfr, acc[t], 0, 0, 0);
        }
    }
    int isf32 = get_isf32(flags);

    // main C write
#pragma unroll
    for (int t = 0; t < NT; ++t) {
        int n = ncol + t * 16 + r;
        bool is0 = n < S0;
        int jc = n - S0;
        float bv = (!is0 && jc < n1 && bias1) ? loadf(bias1, jc, isf32) : 0.f;
#pragma unroll
        for (int j = 0; j < 4; ++j) {
            int m = mrow + 4 * g + j;
            float v = acc[t][j] + bv;
            if (is0) out0[(size_t)m * ld0 + n] = __float2bfloat16(v);
            else if (jc < n1) out1[(size_t)m * ld1 + jc] = v;
        }
    }

    // fused alpha epilogue (NT==4 blocks fully inside [0,S0))
    if (aS && ncol < S0) {
        float ps[2][4], pd[2][4];
#pragma unroll
        for (int hb = 0; hb < 2; ++hb)
#pragma unroll
            for (int j = 0; j < 4; ++j) { ps[hb][j] = 0.f; pd[hb][j] = 0.f; }
#pragma unroll
        for (int t = 0; t < NT; ++t) {
            int col = ncol + t * 16 + r;
            float asv = loadf(aS, col, isf32);
            float adv = loadf(aD, col, isf32);
#pragma unroll
            for (int j = 0; j < 4; ++j) {
                ps[t >> 1][j] += acc[t][j] * asv;
                pd[t >> 1][j] += acc[t][j] * adv;
            }
        }
#pragma unroll
        for (int mk = 1; mk <= 8; mk <<= 1) {
#pragma unroll
            for (int hb = 0; hb < 2; ++hb)
#pragma unroll
                for (int j = 0; j < 4; ++j) {
                    ps[hb][j] += __shfl_xor(ps[hb][j], mk);
                    pd[hb][j] += __shfl_xor(pd[hb][j], mk);
                }
        }
        if (r == 0) {
            int hA = ncol >> 5, hB = hA + 1;
#pragma unroll
            for (int j = 0; j < 4; ++j) {
                int m = mrow + 4 * g + j;
                asrc[(size_t)m * H + hA] = ps[0][j];
                asrc[(size_t)m * H + hB] = ps[1][j];
                adst[(size_t)m * H + hA] = pd[0][j];
                adst[(size_t)m * H + hB] = pd[1][j];
            }
        }
    }
}

// ---------------------------------------------------------------------------
// Fused per-dst-node softmax + aggregation. One wave per dst node, 4 waves/blk.
// mode 1 (F=256, H=8): 4-edge-parallel gather — 16 lanes/edge, 16 ch/lane,
//   2x bf16x8 loads per lane per step (4 edges in flight), shfl_xor(16,32)
//   combine; parallel Pass M across all 64 lanes.
// mode 2 (F=320, H=10): 4-ch granules, 2-edge unrolled dual accumulators;
//   head-mean via per-wave LDS scratch.
// Degree > CAP: slow recompute path.
// ---------------------------------------------------------------------------
#define CAP 96
__global__ void k_fused_agg(const bf16* __restrict__ hlin,
                            const float* __restrict__ asrc, const float* __restrict__ adst,
                            const int* __restrict__ esrc, const int* __restrict__ row_ptr,
                            const int* __restrict__ csr_e,
                            const void* __restrict__ bias, const float* __restrict__ ident,
                            void* __restrict__ out, bf16* __restrict__ outb,
                            const int* __restrict__ flags,
                            int E, int N, int H, int mode) {
    __shared__ float el[4][CAP * 10];   // logits -> exp weights; scratch in mode 2
    __shared__ int   ssrc[4][CAP];
    __shared__ float idn[4][10];
    int wid = threadIdx.x >> 6, lane = threadIdx.x & 63;
    int d = blockIdx.x * 4 + wid;
    bool active = d < N;
    int isf32 = get_isf32(flags);
    int F = H * 32;
    int nj = (F + 255) >> 8;  // 1 (F=256) or 2 (F=320)
    int lo = 0, deg = 0;
    if (active) { lo = row_ptr[d]; deg = row_ptr[d + 1] - lo; }
    bool fast = deg <= CAP;

    // ---- Pass A: logits into LDS ----
    if (active && fast) {
        int EC = 64 / H;
        int h = lane % H, ei = lane / H;
        float ad = adst[(size_t)d * H + h];
        for (int base = 0; base < deg; base += EC) {
            int p = base + ei;
            if (ei < EC && p < deg) {
                int e = csr_e[lo + p];
                int s = (e < E) ? esrc[e] : (e - E);
                float v = asrc[(size_t)s * H + h] + ad;
                v = (v > 0.f) ? v : 0.2f * v;
                el[wid][p * H + h] = v;
                if (h == 0) ssrc[wid][p] = s;
            }
        }
    }
    __syncthreads();
    // ---- Pass M: per-head softmax normalization ----
    if (active && fast) {
        if (H == 8) {
            // all 64 lanes: 8 subs x 8 heads, butterfly over sub bits (8,16,32)
            int h = lane & 7, sub = lane >> 3;
            float m = -1e30f;
            for (int p = sub; p < deg; p += 8) m = fmaxf(m, el[wid][p * 8 + h]);
            m = fmaxf(m, __shfl_xor(m, 8));
            m = fmaxf(m, __shfl_xor(m, 16));
            m = fmaxf(m, __shfl_xor(m, 32));
            float den = 0.f;
            for (int p = sub; p < deg; p += 8) {
                float t = __expf(el[wid][p * 8 + h] - m);
                el[wid][p * 8 + h] = t;
                den += t;
            }
            den += __shfl_xor(den, 8);
            den += __shfl_xor(den, 16);
            den += __shfl_xor(den, 32);
            if (lane < 8) idn[wid][lane] = 1.f / (den + 1e-16f);
        } else if (lane < H) {
            float m = -1e30f;
            for (int p = 0; p < deg; ++p) m = fmaxf(m, el[wid][p * H + lane]);
            float den = 0.f;
            for (int p = 0; p < deg; ++p) {
                float t = __expf(el[wid][p * H + lane] - m);
                el[wid][p * H + lane] = t;
                den += t;
            }
            idn[wid][lane] = 1.f / (den + 1e-16f);
        }
    }
    __syncthreads();
    if (!active) return;

    if (mode == 1 && fast) {
        // ---- 4-edge-parallel gather: F=256, H=8 ----
        int g = lane & 15, q = lane >> 4;   // g: 16-ch group, q: edge offset
        int f0 = g * 16;
        f32x4 a0 = {0.f,0.f,0.f,0.f}, a1 = {0.f,0.f,0.f,0.f};
        f32x4 a2 = {0.f,0.f,0.f,0.f}, a3 = {0.f,0.f,0.f,0.f};
        for (int p = q; p < deg; p += 4) {
            int s = ssrc[wid][p];
            const bf16* hp = hlin + (size_t)s * 256 + f0;
            bf16x8 h0 = *(const bf16x8*)hp;
            bf16x8 h1 = *(const bf16x8*)(hp + 8);
            float w = el[wid][p * 8 + (g >> 1)];
#pragma unroll
            for (int k = 0; k < 4; ++k) {
                a0[k] += w * bf2fs(h0[k]);
                a1[k] += w * bf2fs(h0[4 + k]);
                a2[k] += w * bf2fs(h1[k]);
                a3[k] += w * bf2fs(h1[4 + k]);
            }
        }
#pragma unroll
        for (int k = 0; k < 4; ++k) {
            a0[k] += __shfl_xor(a0[k], 16); a1[k] += __shfl_xor(a1[k], 16);
            a2[k] += __shfl_xor(a2[k], 16); a3[k] += __shfl_xor(a3[k], 16);
            a0[k] += __shfl_xor(a0[k], 32); a1[k] += __shfl_xor(a1[k], 32);
            a2[k] += __shfl_xor(a2[k], 32); a3[k] += __shfl_xor(a3[k], 32);
        }
        if (lane < 16) {
            float inv = idn[wid][g >> 1];
            const float* idp = ident + (size_t)d * 256 + f0;
            float* o = (float*)out + (size_t)d * 256 + f0;
            bf16* ob = outb + (size_t)d * 256 + f0;
            f32x4 av[4] = {a0, a1, a2, a3};
            bf16x8 obv0, obv1;
#pragma unroll
            for (int i = 0; i < 4; ++i) {
                f32x4 idv = *(const f32x4*)(idp + 4 * i);
                f32x4 ov;
#pragma unroll
                for (int k = 0; k < 4; ++k) {
                    float v = av[i][k] * inv + loadf(bias, f0 + 4 * i + k, isf32);
                    v = (v > 0.f) ? v : (__expf(v) - 1.f);  // ELU
                    v += idv[k];
                    ov[k] = v;
                    if (i < 2) obv0[4 * i + k] = f2bfs(v);
                    else       obv1[4 * (i - 2) + k] = f2bfs(v);
                }
                *(f32x4*)(o + 4 * i) = ov;
            }
            *(bf16x8*)ob = obv0;
            *(bf16x8*)(ob + 8) = obv1;
        }
        return;
    }

    // ---- generic path (mode 2 fast, or slow path any mode) ----
    f32x4 acc[2] = {(f32x4){0.f,0.f,0.f,0.f}, (f32x4){0.f,0.f,0.f,0.f}};
    if (fast) {
        // 2-edge unrolled, dual accumulators for MLP
        f32x4 accB[2] = {(f32x4){0.f,0.f,0.f,0.f}, (f32x4){0.f,0.f,0.f,0.f}};
        int hj0 = lane >> 3;            // head of channels lane*4..+3
        int p = 0;
        for (; p + 1 < deg; p += 2) {
            int s0 = ssrc[wid][p], s1 = ssrc[wid][p + 1];
            bf16x4 h00 = *(const bf16x4*)(hlin + (size_t)s0 * F + lane * 4);
            bf16x4 h10 = *(const bf16x4*)(hlin + (size_t)s1 * F + lane * 4);
            float w00 = el[wid][p * H + hj0];
            float w10 = el[wid][(p + 1) * H + hj0];
#pragma unroll
            for (int k = 0; k < 4; ++k) {
                acc[0][k]  += w00 * bf2fs(h00[k]);
                accB[0][k] += w10 * bf2fs(h10[k]);
            }
            if (nj == 2 && lane < 16) {
                int f1 = 256 + lane * 4;
                bf16x4 h01 = *(const bf16x4*)(hlin + (size_t)s0 * F + f1);
                bf16x4 h11 = *(const bf16x4*)(hlin + (size_t)s1 * F + f1);
                float w01 = el[wid][p * H + 8 + hj0];
                float w11 = el[wid][(p + 1) * H + 8 + hj0];
#pragma unroll
                for (int k = 0; k < 4; ++k) {
                    acc[1][k]  += w01 * bf2fs(h01[k]);
                    accB[1][k] += w11 * bf2fs(h11[k]);
                }
            }
        }
        if (p < deg) {  // odd tail
            int s0 = ssrc[wid][p];
            bf16x4 h00 = *(const bf16x4*)(hlin + (size_t)s0 * F + lane * 4);
            float w00 = el[wid][p * H + hj0];
#pragma unroll
            for (int k = 0; k < 4; ++k) acc[0][k] += w00 * bf2fs(h00[k]);
            if (nj == 2 && lane < 16) {
                int f1 = 256 + lane * 4;
                bf16x4 h01 = *(const bf16x4*)(hlin + (size_t)s0 * F + f1);
                float w01 = el[wid][p * H + 8 + hj0];
#pragma unroll
                for (int k = 0; k < 4; ++k) acc[1][k] += w01 * bf2fs(h01[k]);
            }
        }
#pragma unroll
        for (int j = 0; j < 2; ++j)
#pragma unroll
            for (int k = 0; k < 4; ++k) acc[j][k] += accB[j][k];
        // normalize
        {
            float inv0 = idn[wid][hj0];
#pragma unroll
            for (int k = 0; k < 4; ++k) acc[0][k] *= inv0;
            if (nj == 2 && lane < 16) {
                float inv1 = idn[wid][8 + hj0];
#pragma unroll
                for (int k = 0; k < 4; ++k) acc[1][k] *= inv1;
            }
        }
    } else {
        for (int j = 0; j < nj; ++j) {
            int f0 = (lane + 64 * j) * 4;
            if (f0 >= F) continue;
            int hj = f0 >> 5;
            float ad = adst[(size_t)d * H + hj];
            float m = -1e30f;
            for (int p = 0; p < deg; ++p) {
                int e = csr_e[lo + p];
                int s = (e < E) ? esrc[e] : (e - E);
                float v = asrc[(size_t)s * H + hj] + ad;
                v = (v > 0.f) ? v : 0.2f * v;
                m = fmaxf(m, v);
            }
            float den = 0.f;
            f32x4 a4 = {0.f, 0.f, 0.f, 0.f};
            for (int p = 0; p < deg; ++p) {
                int e = csr_e[lo + p];
                int s = (e < E) ? esrc[e] : (e - E);
                float v = asrc[(size_t)s * H + hj] + ad;
                v = (v > 0.f) ? v : 0.2f * v;
                float t = __expf(v - m);
                den += t;
                bf16x4 hv = *(const bf16x4*)(hlin + (size_t)s * F + f0);
                for (int k = 0; k < 4; ++k) a4[k] += t * bf2fs(hv[k]);
            }
            float inv = 1.f / (den + 1e-16f);
            for (int k = 0; k < 4; ++k) acc[j][k] = a4[k] * inv;
        }
    }
    // ---- epilogues for generic path ----
    if (mode == 1) {
        float* o = (float*)out;
        int f0 = lane * 4;
        f32x4 idv = *(const f32x4*)(ident + (size_t)d * F + f0);
        f32x4 ov;
        bf16x4 ob;
#pragma unroll
        for (int k = 0; k < 4; ++k) {
            float v = acc[0][k] + loadf(bias, f0 + k, isf32);
            v = (v > 0.f) ? v : (__expf(v) - 1.f);
            v += idv[k];
            ov[k] = v;
            ob[k] = f2bfs(v);
        }
        *(f32x4*)(o + (size_t)d * F + f0) = ov;
        *(bf16x4*)(outb + (size_t)d * F + f0) = ob;
    } else {
        float* scratch = &el[wid][0];
#pragma unroll
        for (int j = 0; j < 2; ++j) {
            int f0 = (lane + 64 * j) * 4;
            if (j < nj && f0 < F) {
#pragma unroll
                for (int k = 0; k < 4; ++k) scratch[f0 + k] = acc[j][k];
            }
        }
        if (lane < 32) {
            float s = 0.f;
            for (int h = 0; h < H; ++h) s += scratch[h * 32 + lane];
            float v = s * (1.f / (float)H) + loadf(bias, lane, isf32)
                    + ident[(size_t)d * 32 + lane];
            if (isf32) ((float*)out)[(size_t)d * 32 + lane] = v;
            else ((bf16*)out)[(size_t)d * 32 + lane] = __float2bfloat16(v);
        }
    }
}

extern "C" void kernel_launch(void* const* d_in, const int* in_sizes, int n_in,
                              void* d_out, int out_size, void* d_ws, size_t ws_size,
                              hipStream_t stream) {
    const int IN = 256, C = 32;
    const int N = in_sizes[0] / IN;
    const int E = in_sizes[1] / 2;
    const int ET = E + N;

    const void* x    = d_in[0];
    const int*  edge = (const int*)d_in[1];
    const void* W1 = d_in[2];
    const void* a1s = d_in[3];
    const void* a1d = d_in[4];
    const void* b1 = d_in[5];
    const void* W2 = d_in[6];
    const void* a2s = d_in[7];
    const void* a2d = d_in[8];
    const void* b2 = d_in[9];
    const void* W3 = d_in[10];
    const void* a3s = d_in[11];
    const void* a3d = d_in[12];
    const void* b3 = d_in[13];
    const void* P1W = d_in[14];
    const void* P1b = d_in[15];
    const void* P3W = d_in[16];
    const void* P3b = d_in[17];

    char* ws = (char*)d_ws;
    size_t off = 0;
    auto alloc = [&](size_t bytes) -> void* {
        void* p = ws + off;
        off = (off + bytes + 255) & ~(size_t)255;
        return p;
    };
    bf16* fxb   = (bf16*)alloc((size_t)N * 256 * 2);    // bf16 input
    bf16* fyb   = (bf16*)alloc((size_t)N * 256 * 2);    // bf16 layer outputs
    bf16* fhb   = (bf16*)alloc((size_t)N * 320 * 2);    // h_lin bf16 (per layer)
    float* fy   = (float*)alloc((size_t)N * 256 * 4);   // f32 layer outputs
    float* fid  = (float*)alloc((size_t)N * 256 * 4);   // identity1 / identity3
    float* fasrc = (float*)alloc((size_t)N * 10 * 4);
    float* fadst = (float*)alloc((size_t)N * 10 * 4);
    bf16* wc1   = (bf16*)alloc((size_t)512 * 256 * 2);  // [W1; P1W]
    bf16* wb2   = (bf16*)alloc((size_t)256 * 256 * 2);
    bf16* wc3   = (bf16*)alloc((size_t)384 * 256 * 2);  // [W3; P3W; 32 pad rows]
    int*  isrc  = (int*)alloc((size_t)E * 4);
    int*  idst  = (int*)alloc((size_t)E * 4);
    int*  irow  = (int*)alloc((size_t)(N + 1) * 4);
    int*  icur  = (int*)alloc((size_t)N * 4);
    int*  icsr  = (int*)alloc((size_t)ET * 4);
    int*  flags = (int*)alloc(4 * 4);
    (void)ws_size;

    auto cdiv = [](int a, int b) { return (a + b - 1) / b; };

    // dtype detection (tiny prefix probe, block-aggregated)
    int nprobe_x = (N * 256 < 16384) ? N * 256 : 16384;
    int nprobe_e = (2 * E < 8192) ? 2 * E : 8192;
    hipMemsetAsync(flags, 0, 16, stream);
    int bx = cdiv(nprobe_x, 256) < 16 ? cdiv(nprobe_x, 256) : 16;
    int be = cdiv(nprobe_e, 256) < 8 ? cdiv(nprobe_e, 256) : 8;
    k_detect<<<bx + be, 256, 0, stream>>>(
        (const unsigned short*)x, edge, flags, nprobe_x, nprobe_e, bx);

    // normalize inputs (single fused cast launch; counts in 8-elem units)
    int c_x = N * 256 / 8, c_w = 256 * 256 / 8, c_w3 = 320 * 256 / 8, c_p3 = 32 * 256 / 8;
    int ctot = c_x + 3 * c_w + c_w3 + c_p3;
    k_cast_all<<<cdiv(ctot, 256), 256, 0, stream>>>(
        x, fxb, c_x,
        W1, wc1, c_w,
        P1W, wc1 + (size_t)256 * 256, c_w,
        W2, wb2, c_w,
        W3, wc3, c_w3,
        P3W, wc3 + (size_t)320 * 256, c_p3,
        flags);

    // CSR over dst (edges + self-loops)
    hipMemsetAsync(icur, 0, (size_t)N * 4, stream);
    k_norm_count<<<cdiv(E, 256), 256, 0, stream>>>(edge, flags, isrc, idst, icur, E);
    k_scan<<<1, 1024, 0, stream>>>(icur, irow, N);
    k_fill<<<cdiv(ET, 256), 256, 0, stream>>>(idst, icur, irow, icsr, E, N);

    int gx = cdiv(N, 64);
    int ga = cdiv(N, 4);

    // ---- Layer 1: H=8; combined [W1;P1W] GEMM + fused alpha ----
    {
        int H = 8;
        k_gemm_split<4><<<dim3(gx, 8), 256, 0, stream>>>(
            fxb, wc1, P1b, flags, fhb, 256, 256, fid, 256, 256, N, 512, 256,
            a1s, a1d, fasrc, fadst, H);
        k_fused_agg<<<ga, 256, 0, stream>>>(fhb, fasrc, fadst, isrc, irow, icsr, b1, fid, fy, fyb, flags, E, N, H, 1);
    }
    // ---- Layer 2: H=8, identity = layer-1 output ----
    {
        int H = 8;
        k_gemm_split<4><<<dim3(gx, 4), 256, 0, stream>>>(
            fyb, wb2, nullptr, flags, fhb, 256, 256, nullptr, 0, 0, N, 256, 256,
            a2s, a2d, fasrc, fadst, H);
        k_fused_agg<<<ga, 256, 0, stream>>>(fhb, fasrc, fadst, isrc, irow, icsr, b2, fy, fy, fyb, flags, E, N, H, 1);
    }
    // ---- Layer 3: H=10, concat=False; combined [W3;P3W;pad] GEMM ----
    {
        int H = 10;
        k_gemm_split<4><<<dim3(gx, 6), 256, 0, stream>>>(
            fyb, wc3, P3b, flags, fhb, 320, 320, fid, 32, 32, N, 384, 256,
            a3s, a3d, fasrc, fadst, H);
        k_fused_agg<<<ga, 256, 0, stream>>>(fhb, fasrc, fadst, isrc, irow, icsr, b3, fid, d_out, nullptr, flags, E, N, H, 2);
    }
}

// Round 9
// 215.542 us; speedup vs baseline: 6.8000x; 1.0464x over previous
//
#include <hip/hip_runtime.h>
#include <hip/hip_bf16.h>

typedef __hip_bfloat16 bf16;
typedef __attribute__((ext_vector_type(8))) short bf16x8;
typedef __attribute__((ext_vector_type(4))) short bf16x4;
typedef __attribute__((ext_vector_type(4))) float f32x4;

// ---------------------------------------------------------------------------
// 3-layer GAT forward. Dtype-adaptive (observed world: floats=bf16, edges=i32).
// flags[0]=1 if NaN/Inf ushort pattern in x-prefix (=> x is f32)
// flags[1]=1 if any odd 32-bit word of edge prefix nonzero (=> edges i32)
// flags[2]=1 if any even-index ushort of x-prefix nonzero
// isf32 = flags[0] || !flags[2]
// ---------------------------------------------------------------------------

static __device__ __forceinline__ float bf2f(bf16 v) { return __bfloat162float(v); }
static __device__ __forceinline__ float bf2fs(short v) {
    unsigned int u = ((unsigned int)(unsigned short)v) << 16;
    return __builtin_bit_cast(float, u);
}
static __device__ __forceinline__ short f2bfs(float f) {
    bf16 b = __float2bfloat16(f);
    return __builtin_bit_cast(short, b);
}
static __device__ __forceinline__ float loadf(const void* p, size_t i, int isf32) {
    return isf32 ? ((const float*)p)[i] : bf2f(((const bf16*)p)[i]);
}
static __device__ __forceinline__ int get_isf32(const int* flags) {
    return (flags[0] | (flags[2] == 0)) ? 1 : 0;
}

// zero flags[4] + cnt[N] (replaces graph-captured hipMemsetAsync: 41.7us -> ~2us)
__global__ void k_zero(int* __restrict__ flags, int* __restrict__ cnt, int N) {
    int i = blockIdx.x * blockDim.x + threadIdx.x;
    if (i < 4) flags[i] = 0;
    for (; i < N; i += gridDim.x * blockDim.x) cnt[i] = 0;
}

// detection: tiny probe, LDS block aggregation, <=3 atomics per block.
__global__ void k_detect(const unsigned short* __restrict__ xu, const int* __restrict__ ew,
                         int* __restrict__ flags, int nx, int ne2, int bx) {
    __shared__ int lf[3];
    if (threadIdx.x < 3) lf[threadIdx.x] = 0;
    __syncthreads();
    if ((int)blockIdx.x < bx) {
        for (int i = blockIdx.x * 256 + threadIdx.x; i < nx; i += bx * 256) {
            unsigned short v = xu[i];
            if ((v & 0x7F80u) == 0x7F80u) lf[0] = 1;
            if (((i & 1) == 0) && v != 0) lf[2] = 1;
        }
    } else {
        int nb = gridDim.x - bx;
        for (int i = (blockIdx.x - bx) * 256 + threadIdx.x; i < ne2; i += nb * 256) {
            if ((i & 1) && ew[i] != 0) lf[1] = 1;
        }
    }
    __syncthreads();
    if (threadIdx.x == 0) {
        if (lf[0]) atomicOr(&flags[0], 1);
        if (lf[1]) atomicOr(&flags[1], 1);
        if (lf[2]) atomicOr(&flags[2], 1);
    }
}

// 8-elem vectorized adaptive cast
static __device__ __forceinline__ void cast8(const void* src, bf16* dst, int i8, int isf32) {
    if (isf32) {
        f32x4 a = ((const f32x4*)src)[2 * i8];
        f32x4 b = ((const f32x4*)src)[2 * i8 + 1];
        bf16x8 o;
        o[0] = f2bfs(a[0]); o[1] = f2bfs(a[1]); o[2] = f2bfs(a[2]); o[3] = f2bfs(a[3]);
        o[4] = f2bfs(b[0]); o[5] = f2bfs(b[1]); o[6] = f2bfs(b[2]); o[7] = f2bfs(b[3]);
        ((bf16x8*)dst)[i8] = o;
    } else {
        ((bf16x8*)dst)[i8] = ((const bf16x8*)src)[i8];
    }
}

// all input casts in one launch (counts are in 8-elem units)
__global__ void k_cast_all(const void* s0, bf16* d0, int c0,
                           const void* s1, bf16* d1, int c1,
                           const void* s2, bf16* d2, int c2,
                           const void* s3, bf16* d3, int c3,
                           const void* s4, bf16* d4, int c4,
                           const void* s5, bf16* d5, int c5,
                           const int* __restrict__ flags) {
    int t = blockIdx.x * blockDim.x + threadIdx.x;
    int isf32 = get_isf32(flags);
    if (t < c0) { cast8(s0, d0, t, isf32); return; } t -= c0;
    if (t < c1) { cast8(s1, d1, t, isf32); return; } t -= c1;
    if (t < c2) { cast8(s2, d2, t, isf32); return; } t -= c2;
    if (t < c3) { cast8(s3, d3, t, isf32); return; } t -= c3;
    if (t < c4) { cast8(s4, d4, t, isf32); return; } t -= c4;
    if (t < c5) { cast8(s5, d5, t, isf32); }
}

// normalize edges to int32 src/dst + in-degree count (fused)
__global__ void k_norm_count(const int* __restrict__ w, const int* __restrict__ flags,
                             int* __restrict__ s, int* __restrict__ d,
                             int* __restrict__ cnt, int E) {
    int e = blockIdx.x * blockDim.x + threadIdx.x;
    if (e >= E) return;
    int sv, dv;
    if (flags[1] == 0) {  // int64
        sv = w[2 * (size_t)e];
        dv = w[2 * (size_t)E + 2 * (size_t)e];
    } else {              // int32
        sv = w[e];
        dv = w[(size_t)E + e];
    }
    s[e] = sv;
    d[e] = dv;
    atomicAdd(&cnt[dv], 1);
}

// single-block vertical scan: each thread owns a contiguous strip (~N/1024),
// one 1024-wide LDS scan (22 syncs total). Outputs:
//   row_ptr[i+1] = inclusive prefix of (cnt[i]+1); cnt[i] := exclusive prefix.
__global__ void k_scan(int* __restrict__ cnt, int* __restrict__ row_ptr, int N) {
    __shared__ int part[1024];
    int tid = threadIdx.x;
    int vpt = (N + 1023) >> 10;
    int i0 = tid * vpt;
    int i1 = i0 + vpt; if (i1 > N) i1 = N;
    int s = 0;
    for (int i = i0; i < i1; ++i) s += cnt[i] + 1;
    part[tid] = s;
    __syncthreads();
    for (int off = 1; off < 1024; off <<= 1) {
        int t = (tid >= off) ? part[tid - off] : 0;
        __syncthreads();
        part[tid] += t;
        __syncthreads();
    }
    int run = (tid == 0) ? 0 : part[tid - 1];
    for (int i = i0; i < i1; ++i) {
        int c = cnt[i] + 1;
        cnt[i] = run;            // cursor = exclusive prefix
        run += c;
        row_ptr[i + 1] = run;
    }
    if (tid == 0) row_ptr[0] = 0;
}

// fill CSR: edges via atomic cursor; self-loop of node d at row_ptr[d+1]-1.
__global__ void k_fill(const int* __restrict__ edst, int* __restrict__ cursor,
                       const int* __restrict__ row_ptr, int* __restrict__ csr_e,
                       int E, int N) {
    int e = blockIdx.x * blockDim.x + threadIdx.x;
    if (e < E) {
        int d = edst[e];
        int pos = atomicAdd(&cursor[d], 1);
        csr_e[pos] = e;
    } else if (e < E + N) {
        int d = e - E;
        csr_e[row_ptr[d + 1] - 1] = e;
    }
}

// ---------------------------------------------------------------------------
// Unified MFMA GEMM, split output + fused attention-logit epilogue.
// C[M,Fo] = A[M,K](bf16) * W[Fo,K](bf16)^T.
//   cols [0,S0) -> out0 (bf16, ld0); cols [S0,S0+n1) -> out1 (f32, ld1, +bias1);
//   cols >= S0+n1 discarded. If aS: per-row alpha dots for cols in [0,S0)
//   (NT==4: 64 cols = 2 whole heads).
// ---------------------------------------------------------------------------
template<int NT>
__global__ void k_gemm_split(const bf16* __restrict__ A, const bf16* __restrict__ W,
                             const void* __restrict__ bias1, const int* __restrict__ flags,
                             bf16* __restrict__ out0, int S0, int ld0,
                             float* __restrict__ out1, int ld1, int n1,
                             int M, int Fo, int K,
                             const void* __restrict__ aS, const void* __restrict__ aD,
                             float* __restrict__ asrc, float* __restrict__ adst, int H) {
    int wid = threadIdx.x >> 6;
    int lane = threadIdx.x & 63;
    int mrow = blockIdx.x * 64 + wid * 16;
    if (mrow >= M) return;
    int ncol = blockIdx.y * (NT * 16);
    int r = lane & 15, g = lane >> 4;

    f32x4 acc[NT];
#pragma unroll
    for (int t = 0; t < NT; ++t) acc[t] = (f32x4){0.f, 0.f, 0.f, 0.f};

    const bf16* arow = A + (size_t)(mrow + r) * K + g * 8;
    const bf16* wbase = W + (size_t)(ncol + r) * K + g * 8;
    for (int k0 = 0; k0 < K; k0 += 32) {
        bf16x8 af = *(const bf16x8*)(arow + k0);
#pragma unroll
        for (int t = 0; t < NT; ++t) {
            bf16x8 bfr = *(const bf16x8*)(wbase + (size_t)t * 16 * K + k0);
            acc[t] = __builtin_amdgcn_mfma_f32_16x16x32_bf16(af, bfr, acc[t], 0, 0, 0);
        }
    }
    int isf32 = get_isf32(flags);

    // main C write
#pragma unroll
    for (int t = 0; t < NT; ++t) {
        int n = ncol + t * 16 + r;
        bool is0 = n < S0;
        int jc = n - S0;
        float bv = (!is0 && jc < n1 && bias1) ? loadf(bias1, jc, isf32) : 0.f;
#pragma unroll
        for (int j = 0; j < 4; ++j) {
            int m = mrow + 4 * g + j;
            float v = acc[t][j] + bv;
            if (is0) out0[(size_t)m * ld0 + n] = __float2bfloat16(v);
            else if (jc < n1) out1[(size_t)m * ld1 + jc] = v;
        }
    }

    // fused alpha epilogue (NT==4 blocks fully inside [0,S0))
    if (aS && ncol < S0) {
        float ps[2][4], pd[2][4];
#pragma unroll
        for (int hb = 0; hb < 2; ++hb)
#pragma unroll
            for (int j = 0; j < 4; ++j) { ps[hb][j] = 0.f; pd[hb][j] = 0.f; }
#pragma unroll
        for (int t = 0; t < NT; ++t) {
            int col = ncol + t * 16 + r;
            float asv = loadf(aS, col, isf32);
            float adv = loadf(aD, col, isf32);
#pragma unroll
            for (int j = 0; j < 4; ++j) {
                ps[t >> 1][j] += acc[t][j] * asv;
                pd[t >> 1][j] += acc[t][j] * adv;
            }
        }
#pragma unroll
        for (int mk = 1; mk <= 8; mk <<= 1) {
#pragma unroll
            for (int hb = 0; hb < 2; ++hb)
#pragma unroll
                for (int j = 0; j < 4; ++j) {
                    ps[hb][j] += __shfl_xor(ps[hb][j], mk);
                    pd[hb][j] += __shfl_xor(pd[hb][j], mk);
                }
        }
        if (r == 0) {
            int hA = ncol >> 5, hB = hA + 1;
#pragma unroll
            for (int j = 0; j < 4; ++j) {
                int m = mrow + 4 * g + j;
                asrc[(size_t)m * H + hA] = ps[0][j];
                asrc[(size_t)m * H + hB] = ps[1][j];
                adst[(size_t)m * H + hA] = pd[0][j];
                adst[(size_t)m * H + hB] = pd[1][j];
            }
        }
    }
}

// ---------------------------------------------------------------------------
// Fused per-dst-node softmax + aggregation. One wave per dst node, 4 waves/blk.
// mode 1 (F=256, H=8): 4-edge-parallel gather, 16 lanes/edge, 2x bf16x8/lane;
//   parallel Pass M across all 64 lanes.
// mode 2 (F=320, H=10): 4-ch granules, 2-edge dual accumulators; LDS head-mean.
// Degree > CAP: slow recompute path.
// ---------------------------------------------------------------------------
#define CAP 96
__global__ void k_fused_agg(const bf16* __restrict__ hlin,
                            const float* __restrict__ asrc, const float* __restrict__ adst,
                            const int* __restrict__ esrc, const int* __restrict__ row_ptr,
                            const int* __restrict__ csr_e,
                            const void* __restrict__ bias, const float* __restrict__ ident,
                            void* __restrict__ out, bf16* __restrict__ outb,
                            const int* __restrict__ flags,
                            int E, int N, int H, int mode) {
    __shared__ float el[4][CAP * 10];   // logits -> exp weights; scratch in mode 2
    __shared__ int   ssrc[4][CAP];
    __shared__ float idn[4][10];
    int wid = threadIdx.x >> 6, lane = threadIdx.x & 63;
    int d = blockIdx.x * 4 + wid;
    bool active = d < N;
    int isf32 = get_isf32(flags);
    int F = H * 32;
    int nj = (F + 255) >> 8;  // 1 (F=256) or 2 (F=320)
    int lo = 0, deg = 0;
    if (active) { lo = row_ptr[d]; deg = row_ptr[d + 1] - lo; }
    bool fast = deg <= CAP;

    // ---- Pass A: logits into LDS ----
    if (active && fast) {
        int EC = 64 / H;
        int h = lane % H, ei = lane / H;
        float ad = adst[(size_t)d * H + h];
        for (int base = 0; base < deg; base += EC) {
            int p = base + ei;
            if (ei < EC && p < deg) {
                int e = csr_e[lo + p];
                int s = (e < E) ? esrc[e] : (e - E);
                float v = asrc[(size_t)s * H + h] + ad;
                v = (v > 0.f) ? v : 0.2f * v;
                el[wid][p * H + h] = v;
                if (h == 0) ssrc[wid][p] = s;
            }
        }
    }
    __syncthreads();
    // ---- Pass M: per-head softmax normalization ----
    if (active && fast) {
        if (H == 8) {
            int h = lane & 7, sub = lane >> 3;
            float m = -1e30f;
            for (int p = sub; p < deg; p += 8) m = fmaxf(m, el[wid][p * 8 + h]);
            m = fmaxf(m, __shfl_xor(m, 8));
            m = fmaxf(m, __shfl_xor(m, 16));
            m = fmaxf(m, __shfl_xor(m, 32));
            float den = 0.f;
            for (int p = sub; p < deg; p += 8) {
                float t = __expf(el[wid][p * 8 + h] - m);
                el[wid][p * 8 + h] = t;
                den += t;
            }
            den += __shfl_xor(den, 8);
            den += __shfl_xor(den, 16);
            den += __shfl_xor(den, 32);
            if (lane < 8) idn[wid][lane] = 1.f / (den + 1e-16f);
        } else if (lane < H) {
            float m = -1e30f;
            for (int p = 0; p < deg; ++p) m = fmaxf(m, el[wid][p * H + lane]);
            float den = 0.f;
            for (int p = 0; p < deg; ++p) {
                float t = __expf(el[wid][p * H + lane] - m);
                el[wid][p * H + lane] = t;
                den += t;
            }
            idn[wid][lane] = 1.f / (den + 1e-16f);
        }
    }
    __syncthreads();
    if (!active) return;

    if (mode == 1 && fast) {
        // ---- 4-edge-parallel gather: F=256, H=8 ----
        int g = lane & 15, q = lane >> 4;
        int f0 = g * 16;
        f32x4 a0 = {0.f,0.f,0.f,0.f}, a1 = {0.f,0.f,0.f,0.f};
        f32x4 a2 = {0.f,0.f,0.f,0.f}, a3 = {0.f,0.f,0.f,0.f};
        for (int p = q; p < deg; p += 4) {
            int s = ssrc[wid][p];
            const bf16* hp = hlin + (size_t)s * 256 + f0;
            bf16x8 h0 = *(const bf16x8*)hp;
            bf16x8 h1 = *(const bf16x8*)(hp + 8);
            float w = el[wid][p * 8 + (g >> 1)];
#pragma unroll
            for (int k = 0; k < 4; ++k) {
                a0[k] += w * bf2fs(h0[k]);
                a1[k] += w * bf2fs(h0[4 + k]);
                a2[k] += w * bf2fs(h1[k]);
                a3[k] += w * bf2fs(h1[4 + k]);
            }
        }
#pragma unroll
        for (int k = 0; k < 4; ++k) {
            a0[k] += __shfl_xor(a0[k], 16); a1[k] += __shfl_xor(a1[k], 16);
            a2[k] += __shfl_xor(a2[k], 16); a3[k] += __shfl_xor(a3[k], 16);
            a0[k] += __shfl_xor(a0[k], 32); a1[k] += __shfl_xor(a1[k], 32);
            a2[k] += __shfl_xor(a2[k], 32); a3[k] += __shfl_xor(a3[k], 32);
        }
        if (lane < 16) {
            float inv = idn[wid][g >> 1];
            const float* idp = ident + (size_t)d * 256 + f0;
            float* o = (float*)out + (size_t)d * 256 + f0;
            bf16* ob = outb + (size_t)d * 256 + f0;
            f32x4 av[4] = {a0, a1, a2, a3};
            bf16x8 obv0, obv1;
#pragma unroll
            for (int i = 0; i < 4; ++i) {
                f32x4 idv = *(const f32x4*)(idp + 4 * i);
                f32x4 ov;
#pragma unroll
                for (int k = 0; k < 4; ++k) {
                    float v = av[i][k] * inv + loadf(bias, f0 + 4 * i + k, isf32);
                    v = (v > 0.f) ? v : (__expf(v) - 1.f);  // ELU
                    v += idv[k];
                    ov[k] = v;
                    if (i < 2) obv0[4 * i + k] = f2bfs(v);
                    else       obv1[4 * (i - 2) + k] = f2bfs(v);
                }
                *(f32x4*)(o + 4 * i) = ov;
            }
            *(bf16x8*)ob = obv0;
            *(bf16x8*)(ob + 8) = obv1;
        }
        return;
    }

    // ---- generic path (mode 2 fast, or slow path any mode) ----
    f32x4 acc[2] = {(f32x4){0.f,0.f,0.f,0.f}, (f32x4){0.f,0.f,0.f,0.f}};
    if (fast) {
        f32x4 accB[2] = {(f32x4){0.f,0.f,0.f,0.f}, (f32x4){0.f,0.f,0.f,0.f}};
        int hj0 = lane >> 3;
        int p = 0;
        for (; p + 1 < deg; p += 2) {
            int s0 = ssrc[wid][p], s1 = ssrc[wid][p + 1];
            bf16x4 h00 = *(const bf16x4*)(hlin + (size_t)s0 * F + lane * 4);
            bf16x4 h10 = *(const bf16x4*)(hlin + (size_t)s1 * F + lane * 4);
            float w00 = el[wid][p * H + hj0];
            float w10 = el[wid][(p + 1) * H + hj0];
#pragma unroll
            for (int k = 0; k < 4; ++k) {
                acc[0][k]  += w00 * bf2fs(h00[k]);
                accB[0][k] += w10 * bf2fs(h10[k]);
            }
            if (nj == 2 && lane < 16) {
                int f1 = 256 + lane * 4;
                bf16x4 h01 = *(const bf16x4*)(hlin + (size_t)s0 * F + f1);
                bf16x4 h11 = *(const bf16x4*)(hlin + (size_t)s1 * F + f1);
                float w01 = el[wid][p * H + 8 + hj0];
                float w11 = el[wid][(p + 1) * H + 8 + hj0];
#pragma unroll
                for (int k = 0; k < 4; ++k) {
                    acc[1][k]  += w01 * bf2fs(h01[k]);
                    accB[1][k] += w11 * bf2fs(h11[k]);
                }
            }
        }
        if (p < deg) {
            int s0 = ssrc[wid][p];
            bf16x4 h00 = *(const bf16x4*)(hlin + (size_t)s0 * F + lane * 4);
            float w00 = el[wid][p * H + hj0];
#pragma unroll
            for (int k = 0; k < 4; ++k) acc[0][k] += w00 * bf2fs(h00[k]);
            if (nj == 2 && lane < 16) {
                int f1 = 256 + lane * 4;
                bf16x4 h01 = *(const bf16x4*)(hlin + (size_t)s0 * F + f1);
                float w01 = el[wid][p * H + 8 + hj0];
#pragma unroll
                for (int k = 0; k < 4; ++k) acc[1][k] += w01 * bf2fs(h01[k]);
            }
        }
#pragma unroll
        for (int j = 0; j < 2; ++j)
#pragma unroll
            for (int k = 0; k < 4; ++k) acc[j][k] += accB[j][k];
        {
            float inv0 = idn[wid][hj0];
#pragma unroll
            for (int k = 0; k < 4; ++k) acc[0][k] *= inv0;
            if (nj == 2 && lane < 16) {
                float inv1 = idn[wid][8 + hj0];
#pragma unroll
                for (int k = 0; k < 4; ++k) acc[1][k] *= inv1;
            }
        }
    } else {
        for (int j = 0; j < nj; ++j) {
            int f0 = (lane + 64 * j) * 4;
            if (f0 >= F) continue;
            int hj = f0 >> 5;
            float ad = adst[(size_t)d * H + hj];
            float m = -1e30f;
            for (int p = 0; p < deg; ++p) {
                int e = csr_e[lo + p];
                int s = (e < E) ? esrc[e] : (e - E);
                float v = asrc[(size_t)s * H + hj] + ad;
                v = (v > 0.f) ? v : 0.2f * v;
                m = fmaxf(m, v);
            }
            float den = 0.f;
            f32x4 a4 = {0.f, 0.f, 0.f, 0.f};
            for (int p = 0; p < deg; ++p) {
                int e = csr_e[lo + p];
                int s = (e < E) ? esrc[e] : (e - E);
                float v = asrc[(size_t)s * H + hj] + ad;
                v = (v > 0.f) ? v : 0.2f * v;
                float t = __expf(v - m);
                den += t;
                bf16x4 hv = *(const bf16x4*)(hlin + (size_t)s * F + f0);
                for (int k = 0; k < 4; ++k) a4[k] += t * bf2fs(hv[k]);
            }
            float inv = 1.f / (den + 1e-16f);
            for (int k = 0; k < 4; ++k) acc[j][k] = a4[k] * inv;
        }
    }
    // ---- epilogues for generic path ----
    if (mode == 1) {
        float* o = (float*)out;
        int f0 = lane * 4;
        f32x4 idv = *(const f32x4*)(ident + (size_t)d * F + f0);
        f32x4 ov;
        bf16x4 ob;
#pragma unroll
        for (int k = 0; k < 4; ++k) {
            float v = acc[0][k] + loadf(bias, f0 + k, isf32);
            v = (v > 0.f) ? v : (__expf(v) - 1.f);
            v += idv[k];
            ov[k] = v;
            ob[k] = f2bfs(v);
        }
        *(f32x4*)(o + (size_t)d * F + f0) = ov;
        *(bf16x4*)(outb + (size_t)d * F + f0) = ob;
    } else {
        float* scratch = &el[wid][0];
#pragma unroll
        for (int j = 0; j < 2; ++j) {
            int f0 = (lane + 64 * j) * 4;
            if (j < nj && f0 < F) {
#pragma unroll
                for (int k = 0; k < 4; ++k) scratch[f0 + k] = acc[j][k];
            }
        }
        if (lane < 32) {
            float s = 0.f;
            for (int h = 0; h < H; ++h) s += scratch[h * 32 + lane];
            float v = s * (1.f / (float)H) + loadf(bias, lane, isf32)
                    + ident[(size_t)d * 32 + lane];
            if (isf32) ((float*)out)[(size_t)d * 32 + lane] = v;
            else ((bf16*)out)[(size_t)d * 32 + lane] = __float2bfloat16(v);
        }
    }
}

extern "C" void kernel_launch(void* const* d_in, const int* in_sizes, int n_in,
                              void* d_out, int out_size, void* d_ws, size_t ws_size,
                              hipStream_t stream) {
    const int IN = 256, C = 32;
    const int N = in_sizes[0] / IN;
    const int E = in_sizes[1] / 2;
    const int ET = E + N;

    const void* x    = d_in[0];
    const int*  edge = (const int*)d_in[1];
    const void* W1 = d_in[2];
    const void* a1s = d_in[3];
    const void* a1d = d_in[4];
    const void* b1 = d_in[5];
    const void* W2 = d_in[6];
    const void* a2s = d_in[7];
    const void* a2d = d_in[8];
    const void* b2 = d_in[9];
    const void* W3 = d_in[10];
    const void* a3s = d_in[11];
    const void* a3d = d_in[12];
    const void* b3 = d_in[13];
    const void* P1W = d_in[14];
    const void* P1b = d_in[15];
    const void* P3W = d_in[16];
    const void* P3b = d_in[17];

    char* ws = (char*)d_ws;
    size_t off = 0;
    auto alloc = [&](size_t bytes) -> void* {
        void* p = ws + off;
        off = (off + bytes + 255) & ~(size_t)255;
        return p;
    };
    bf16* fxb   = (bf16*)alloc((size_t)N * 256 * 2);    // bf16 input
    bf16* fyb   = (bf16*)alloc((size_t)N * 256 * 2);    // bf16 layer outputs
    bf16* fhb   = (bf16*)alloc((size_t)N * 320 * 2);    // h_lin bf16 (per layer)
    float* fy   = (float*)alloc((size_t)N * 256 * 4);   // f32 layer outputs
    float* fid  = (float*)alloc((size_t)N * 256 * 4);   // identity1 / identity3
    float* fasrc = (float*)alloc((size_t)N * 10 * 4);
    float* fadst = (float*)alloc((size_t)N * 10 * 4);
    bf16* wc1   = (bf16*)alloc((size_t)512 * 256 * 2);  // [W1; P1W]
    bf16* wb2   = (bf16*)alloc((size_t)256 * 256 * 2);
    bf16* wc3   = (bf16*)alloc((size_t)384 * 256 * 2);  // [W3; P3W; 32 pad rows]
    int*  isrc  = (int*)alloc((size_t)E * 4);
    int*  idst  = (int*)alloc((size_t)E * 4);
    int*  irow  = (int*)alloc((size_t)(N + 1) * 4);
    int*  icur  = (int*)alloc((size_t)N * 4);
    int*  icsr  = (int*)alloc((size_t)ET * 4);
    int*  flags = (int*)alloc(4 * 4);
    (void)ws_size;

    auto cdiv = [](int a, int b) { return (a + b - 1) / b; };

    // zero flags + degree counters (no graph-captured memset nodes)
    k_zero<<<cdiv(N, 256), 256, 0, stream>>>(flags, icur, N);

    // dtype detection (tiny prefix probe, block-aggregated)
    int nprobe_x = (N * 256 < 16384) ? N * 256 : 16384;
    int nprobe_e = (2 * E < 8192) ? 2 * E : 8192;
    int bx = cdiv(nprobe_x, 256) < 16 ? cdiv(nprobe_x, 256) : 16;
    int be = cdiv(nprobe_e, 256) < 8 ? cdiv(nprobe_e, 256) : 8;
    k_detect<<<bx + be, 256, 0, stream>>>(
        (const unsigned short*)x, edge, flags, nprobe_x, nprobe_e, bx);

    // normalize inputs (single fused cast launch; counts in 8-elem units)
    int c_x = N * 256 / 8, c_w = 256 * 256 / 8, c_w3 = 320 * 256 / 8, c_p3 = 32 * 256 / 8;
    int ctot = c_x + 3 * c_w + c_w3 + c_p3;
    k_cast_all<<<cdiv(ctot, 256), 256, 0, stream>>>(
        x, fxb, c_x,
        W1, wc1, c_w,
        P1W, wc1 + (size_t)256 * 256, c_w,
        W2, wb2, c_w,
        W3, wc3, c_w3,
        P3W, wc3 + (size_t)320 * 256, c_p3,
        flags);

    // CSR over dst (edges + self-loops)
    k_norm_count<<<cdiv(E, 256), 256, 0, stream>>>(edge, flags, isrc, idst, icur, E);
    k_scan<<<1, 1024, 0, stream>>>(icur, irow, N);
    k_fill<<<cdiv(ET, 256), 256, 0, stream>>>(idst, icur, irow, icsr, E, N);

    int gx = cdiv(N, 64);
    int ga = cdiv(N, 4);

    // ---- Layer 1: H=8; combined [W1;P1W] GEMM + fused alpha ----
    {
        int H = 8;
        k_gemm_split<4><<<dim3(gx, 8), 256, 0, stream>>>(
            fxb, wc1, P1b, flags, fhb, 256, 256, fid, 256, 256, N, 512, 256,
            a1s, a1d, fasrc, fadst, H);
        k_fused_agg<<<ga, 256, 0, stream>>>(fhb, fasrc, fadst, isrc, irow, icsr, b1, fid, fy, fyb, flags, E, N, H, 1);
    }
    // ---- Layer 2: H=8, identity = layer-1 output ----
    {
        int H = 8;
        k_gemm_split<4><<<dim3(gx, 4), 256, 0, stream>>>(
            fyb, wb2, nullptr, flags, fhb, 256, 256, nullptr, 0, 0, N, 256, 256,
            a2s, a2d, fasrc, fadst, H);
        k_fused_agg<<<ga, 256, 0, stream>>>(fhb, fasrc, fadst, isrc, irow, icsr, b2, fy, fy, fyb, flags, E, N, H, 1);
    }
    // ---- Layer 3: H=10, concat=False; combined [W3;P3W;pad] GEMM ----
    {
        int H = 10;
        k_gemm_split<4><<<dim3(gx, 6), 256, 0, stream>>>(
            fyb, wc3, P3b, flags, fhb, 320, 320, fid, 32, 32, N, 384, 256,
            a3s, a3d, fasrc, fadst, H);
        k_fused_agg<<<ga, 256, 0, stream>>>(fhb, fasrc, fadst, isrc, irow, icsr, b3, fid, d_out, nullptr, flags, E, N, H, 2);
    }
}

// Round 10
// 202.868 us; speedup vs baseline: 7.2249x; 1.0625x over previous
//
#include <hip/hip_runtime.h>
#include <hip/hip_bf16.h>

typedef __hip_bfloat16 bf16;
typedef __attribute__((ext_vector_type(8))) short bf16x8;
typedef __attribute__((ext_vector_type(4))) short bf16x4;
typedef __attribute__((ext_vector_type(4))) float f32x4;

// ---------------------------------------------------------------------------
// 3-layer GAT forward. Dtype-adaptive (observed world: floats=bf16, edges=i32).
// flags[0]=1 if NaN/Inf ushort pattern in x-prefix (=> x is f32)
// flags[1]=1 if any odd 32-bit word of edge prefix nonzero (=> edges i32)
// flags[2]=1 if any even-index ushort of x-prefix nonzero
// isf32 = flags[0] || !flags[2]
// All activations + identities kept in bf16 (residual rounding ~2^-9, within
// the bf16 threshold budget). Only final out is dtype-adaptive.
// ---------------------------------------------------------------------------

static __device__ __forceinline__ float bf2f(bf16 v) { return __bfloat162float(v); }
static __device__ __forceinline__ float bf2fs(short v) {
    unsigned int u = ((unsigned int)(unsigned short)v) << 16;
    return __builtin_bit_cast(float, u);
}
static __device__ __forceinline__ short f2bfs(float f) {
    bf16 b = __float2bfloat16(f);
    return __builtin_bit_cast(short, b);
}
static __device__ __forceinline__ float loadf(const void* p, size_t i, int isf32) {
    return isf32 ? ((const float*)p)[i] : bf2f(((const bf16*)p)[i]);
}
static __device__ __forceinline__ int get_isf32(const int* flags) {
    return (flags[0] | (flags[2] == 0)) ? 1 : 0;
}

// zero flags[4] + cnt[N]
__global__ void k_zero(int* __restrict__ flags, int* __restrict__ cnt, int N) {
    int i = blockIdx.x * blockDim.x + threadIdx.x;
    if (i < 4) flags[i] = 0;
    for (; i < N; i += gridDim.x * blockDim.x) cnt[i] = 0;
}

// detection: tiny probe, LDS block aggregation, <=3 atomics per block.
__global__ void k_detect(const unsigned short* __restrict__ xu, const int* __restrict__ ew,
                         int* __restrict__ flags, int nx, int ne2, int bx) {
    __shared__ int lf[3];
    if (threadIdx.x < 3) lf[threadIdx.x] = 0;
    __syncthreads();
    if ((int)blockIdx.x < bx) {
        for (int i = blockIdx.x * 256 + threadIdx.x; i < nx; i += bx * 256) {
            unsigned short v = xu[i];
            if ((v & 0x7F80u) == 0x7F80u) lf[0] = 1;
            if (((i & 1) == 0) && v != 0) lf[2] = 1;
        }
    } else {
        int nb = gridDim.x - bx;
        for (int i = (blockIdx.x - bx) * 256 + threadIdx.x; i < ne2; i += nb * 256) {
            if ((i & 1) && ew[i] != 0) lf[1] = 1;
        }
    }
    __syncthreads();
    if (threadIdx.x == 0) {
        if (lf[0]) atomicOr(&flags[0], 1);
        if (lf[1]) atomicOr(&flags[1], 1);
        if (lf[2]) atomicOr(&flags[2], 1);
    }
}

// 8-elem vectorized adaptive cast
static __device__ __forceinline__ void cast8(const void* src, bf16* dst, int i8, int isf32) {
    if (isf32) {
        f32x4 a = ((const f32x4*)src)[2 * i8];
        f32x4 b = ((const f32x4*)src)[2 * i8 + 1];
        bf16x8 o;
        o[0] = f2bfs(a[0]); o[1] = f2bfs(a[1]); o[2] = f2bfs(a[2]); o[3] = f2bfs(a[3]);
        o[4] = f2bfs(b[0]); o[5] = f2bfs(b[1]); o[6] = f2bfs(b[2]); o[7] = f2bfs(b[3]);
        ((bf16x8*)dst)[i8] = o;
    } else {
        ((bf16x8*)dst)[i8] = ((const bf16x8*)src)[i8];
    }
}

// all input casts in one launch (counts are in 8-elem units)
__global__ void k_cast_all(const void* s0, bf16* d0, int c0,
                           const void* s1, bf16* d1, int c1,
                           const void* s2, bf16* d2, int c2,
                           const void* s3, bf16* d3, int c3,
                           const void* s4, bf16* d4, int c4,
                           const void* s5, bf16* d5, int c5,
                           const int* __restrict__ flags) {
    int t = blockIdx.x * blockDim.x + threadIdx.x;
    int isf32 = get_isf32(flags);
    if (t < c0) { cast8(s0, d0, t, isf32); return; } t -= c0;
    if (t < c1) { cast8(s1, d1, t, isf32); return; } t -= c1;
    if (t < c2) { cast8(s2, d2, t, isf32); return; } t -= c2;
    if (t < c3) { cast8(s3, d3, t, isf32); return; } t -= c3;
    if (t < c4) { cast8(s4, d4, t, isf32); return; } t -= c4;
    if (t < c5) { cast8(s5, d5, t, isf32); }
}

// normalize edges to int32 src/dst + in-degree count (fused)
__global__ void k_norm_count(const int* __restrict__ w, const int* __restrict__ flags,
                             int* __restrict__ s, int* __restrict__ d,
                             int* __restrict__ cnt, int E) {
    int e = blockIdx.x * blockDim.x + threadIdx.x;
    if (e >= E) return;
    int sv, dv;
    if (flags[1] == 0) {  // int64
        sv = w[2 * (size_t)e];
        dv = w[2 * (size_t)E + 2 * (size_t)e];
    } else {              // int32
        sv = w[e];
        dv = w[(size_t)E + e];
    }
    s[e] = sv;
    d[e] = dv;
    atomicAdd(&cnt[dv], 1);
}

// single-block vertical scan: thread-strips + one 1024-wide LDS scan.
__global__ void k_scan(int* __restrict__ cnt, int* __restrict__ row_ptr, int N) {
    __shared__ int part[1024];
    int tid = threadIdx.x;
    int vpt = (N + 1023) >> 10;
    int i0 = tid * vpt;
    int i1 = i0 + vpt; if (i1 > N) i1 = N;
    int s = 0;
    for (int i = i0; i < i1; ++i) s += cnt[i] + 1;
    part[tid] = s;
    __syncthreads();
    for (int off = 1; off < 1024; off <<= 1) {
        int t = (tid >= off) ? part[tid - off] : 0;
        __syncthreads();
        part[tid] += t;
        __syncthreads();
    }
    int run = (tid == 0) ? 0 : part[tid - 1];
    for (int i = i0; i < i1; ++i) {
        int c = cnt[i] + 1;
        cnt[i] = run;            // cursor = exclusive prefix
        run += c;
        row_ptr[i + 1] = run;
    }
    if (tid == 0) row_ptr[0] = 0;
}

// fill CSR: edges via atomic cursor; self-loop of node d at row_ptr[d+1]-1.
__global__ void k_fill(const int* __restrict__ edst, int* __restrict__ cursor,
                       const int* __restrict__ row_ptr, int* __restrict__ csr_e,
                       int E, int N) {
    int e = blockIdx.x * blockDim.x + threadIdx.x;
    if (e < E) {
        int d = edst[e];
        int pos = atomicAdd(&cursor[d], 1);
        csr_e[pos] = e;
    } else if (e < E + N) {
        int d = e - E;
        csr_e[row_ptr[d + 1] - 1] = e;
    }
}

// ---------------------------------------------------------------------------
// Unified MFMA GEMM, split output (both bf16) + fused attention-logit epilogue.
// C[M,Fo] = A[M,K](bf16) * W[Fo,K](bf16)^T.
//   cols [0,S0) -> out0 (bf16, ld0); cols [S0,S0+n1) -> out1 (bf16, ld1, +bias1);
//   cols >= S0+n1 discarded. If aS: per-row alpha dots for cols in [0,S0).
// ---------------------------------------------------------------------------
template<int NT>
__global__ void k_gemm_split(const bf16* __restrict__ A, const bf16* __restrict__ W,
                             const void* __restrict__ bias1, const int* __restrict__ flags,
                             bf16* __restrict__ out0, int S0, int ld0,
                             bf16* __restrict__ out1, int ld1, int n1,
                             int M, int Fo, int K,
                             const void* __restrict__ aS, const void* __restrict__ aD,
                             float* __restrict__ asrc, float* __restrict__ adst, int H) {
    int wid = threadIdx.x >> 6;
    int lane = threadIdx.x & 63;
    int mrow = blockIdx.x * 64 + wid * 16;
    if (mrow >= M) return;
    int ncol = blockIdx.y * (NT * 16);
    int r = lane & 15, g = lane >> 4;

    f32x4 acc[NT];
#pragma unroll
    for (int t = 0; t < NT; ++t) acc[t] = (f32x4){0.f, 0.f, 0.f, 0.f};

    const bf16* arow = A + (size_t)(mrow + r) * K + g * 8;
    const bf16* wbase = W + (size_t)(ncol + r) * K + g * 8;
    for (int k0 = 0; k0 < K; k0 += 32) {
        bf16x8 af = *(const bf16x8*)(arow + k0);
#pragma unroll
        for (int t = 0; t < NT; ++t) {
            bf16x8 bfr = *(const bf16x8*)(wbase + (size_t)t * 16 * K + k0);
            acc[t] = __builtin_amdgcn_mfma_f32_16x16x32_bf16(af, bfr, acc[t], 0, 0, 0);
        }
    }
    int isf32 = get_isf32(flags);

    // main C write
#pragma unroll
    for (int t = 0; t < NT; ++t) {
        int n = ncol + t * 16 + r;
        bool is0 = n < S0;
        int jc = n - S0;
        float bv = (!is0 && jc < n1 && bias1) ? loadf(bias1, jc, isf32) : 0.f;
#pragma unroll
        for (int j = 0; j < 4; ++j) {
            int m = mrow + 4 * g + j;
            float v = acc[t][j] + bv;
            if (is0) out0[(size_t)m * ld0 + n] = __float2bfloat16(v);
            else if (jc < n1) out1[(size_t)m * ld1 + jc] = __float2bfloat16(v);
        }
    }

    // fused alpha epilogue (NT==4 blocks fully inside [0,S0): 2 whole heads)
    if (aS && ncol < S0) {
        float ps[2][4], pd[2][4];
#pragma unroll
        for (int hb = 0; hb < 2; ++hb)
#pragma unroll
            for (int j = 0; j < 4; ++j) { ps[hb][j] = 0.f; pd[hb][j] = 0.f; }
#pragma unroll
        for (int t = 0; t < NT; ++t) {
            int col = ncol + t * 16 + r;
            float asv = loadf(aS, col, isf32);
            float adv = loadf(aD, col, isf32);
#pragma unroll
            for (int j = 0; j < 4; ++j) {
                ps[t >> 1][j] += acc[t][j] * asv;
                pd[t >> 1][j] += acc[t][j] * adv;
            }
        }
#pragma unroll
        for (int mk = 1; mk <= 8; mk <<= 1) {
#pragma unroll
            for (int hb = 0; hb < 2; ++hb)
#pragma unroll
                for (int j = 0; j < 4; ++j) {
                    ps[hb][j] += __shfl_xor(ps[hb][j], mk);
                    pd[hb][j] += __shfl_xor(pd[hb][j], mk);
                }
        }
        if (r == 0) {
            int hA = ncol >> 5, hB = hA + 1;
#pragma unroll
            for (int j = 0; j < 4; ++j) {
                int m = mrow + 4 * g + j;
                asrc[(size_t)m * H + hA] = ps[0][j];
                asrc[(size_t)m * H + hB] = ps[1][j];
                adst[(size_t)m * H + hA] = pd[0][j];
                adst[(size_t)m * H + hB] = pd[1][j];
            }
        }
    }
}

// ---------------------------------------------------------------------------
// Fused per-dst-node softmax + aggregation. One wave per dst node, 4 waves/blk.
// mode 1 (F=256, H=8): 4-edge-parallel gather, 16 lanes/edge, 2x bf16x8/lane.
// mode 2 (F=320, H=10): 4-edge-parallel, 16 lanes/edge, 2x bf16x8 + 1x bf16x4;
//   head-mean via per-wave LDS scratch.
// ident is bf16 everywhere. Degree > CAP: slow recompute path.
// ---------------------------------------------------------------------------
#define CAP 96
__global__ void k_fused_agg(const bf16* __restrict__ hlin,
                            const float* __restrict__ asrc, const float* __restrict__ adst,
                            const int* __restrict__ esrc, const int* __restrict__ row_ptr,
                            const int* __restrict__ csr_e,
                            const void* __restrict__ bias, const bf16* __restrict__ identb,
                            void* __restrict__ out, bf16* __restrict__ outb,
                            const int* __restrict__ flags,
                            int E, int N, int H, int mode) {
    __shared__ float el[4][CAP * 10];   // logits -> exp weights; scratch in mode 2
    __shared__ int   ssrc[4][CAP];
    __shared__ float idn[4][10];
    int wid = threadIdx.x >> 6, lane = threadIdx.x & 63;
    int d = blockIdx.x * 4 + wid;
    bool active = d < N;
    int isf32 = get_isf32(flags);
    int F = H * 32;
    int nj = (F + 255) >> 8;  // 1 (F=256) or 2 (F=320)
    int lo = 0, deg = 0;
    if (active) { lo = row_ptr[d]; deg = row_ptr[d + 1] - lo; }
    bool fast = deg <= CAP;

    // ---- Pass A: logits into LDS ----
    if (active && fast) {
        int EC = 64 / H;
        int h = lane % H, ei = lane / H;
        float ad = adst[(size_t)d * H + h];
        for (int base = 0; base < deg; base += EC) {
            int p = base + ei;
            if (ei < EC && p < deg) {
                int e = csr_e[lo + p];
                int s = (e < E) ? esrc[e] : (e - E);
                float v = asrc[(size_t)s * H + h] + ad;
                v = (v > 0.f) ? v : 0.2f * v;
                el[wid][p * H + h] = v;
                if (h == 0) ssrc[wid][p] = s;
            }
        }
    }
    __syncthreads();
    // ---- Pass M: per-head softmax normalization ----
    if (active && fast) {
        if (H == 8) {
            int h = lane & 7, sub = lane >> 3;
            float m = -1e30f;
            for (int p = sub; p < deg; p += 8) m = fmaxf(m, el[wid][p * 8 + h]);
            m = fmaxf(m, __shfl_xor(m, 8));
            m = fmaxf(m, __shfl_xor(m, 16));
            m = fmaxf(m, __shfl_xor(m, 32));
            float den = 0.f;
            for (int p = sub; p < deg; p += 8) {
                float t = __expf(el[wid][p * 8 + h] - m);
                el[wid][p * 8 + h] = t;
                den += t;
            }
            den += __shfl_xor(den, 8);
            den += __shfl_xor(den, 16);
            den += __shfl_xor(den, 32);
            if (lane < 8) idn[wid][lane] = 1.f / (den + 1e-16f);
        } else if (lane < H) {
            float m = -1e30f;
            for (int p = 0; p < deg; ++p) m = fmaxf(m, el[wid][p * H + lane]);
            float den = 0.f;
            for (int p = 0; p < deg; ++p) {
                float t = __expf(el[wid][p * H + lane] - m);
                el[wid][p * H + lane] = t;
                den += t;
            }
            idn[wid][lane] = 1.f / (den + 1e-16f);
        }
    }
    __syncthreads();
    if (!active) return;

    if (mode == 1 && fast) {
        // ---- 4-edge-parallel gather: F=256, H=8 ----
        int g = lane & 15, q = lane >> 4;
        int f0 = g * 16;
        f32x4 a0 = {0.f,0.f,0.f,0.f}, a1 = {0.f,0.f,0.f,0.f};
        f32x4 a2 = {0.f,0.f,0.f,0.f}, a3 = {0.f,0.f,0.f,0.f};
        for (int p = q; p < deg; p += 4) {
            int s = ssrc[wid][p];
            const bf16* hp = hlin + (size_t)s * 256 + f0;
            bf16x8 h0 = *(const bf16x8*)hp;
            bf16x8 h1 = *(const bf16x8*)(hp + 8);
            float w = el[wid][p * 8 + (g >> 1)];
#pragma unroll
            for (int k = 0; k < 4; ++k) {
                a0[k] += w * bf2fs(h0[k]);
                a1[k] += w * bf2fs(h0[4 + k]);
                a2[k] += w * bf2fs(h1[k]);
                a3[k] += w * bf2fs(h1[4 + k]);
            }
        }
#pragma unroll
        for (int k = 0; k < 4; ++k) {
            a0[k] += __shfl_xor(a0[k], 16); a1[k] += __shfl_xor(a1[k], 16);
            a2[k] += __shfl_xor(a2[k], 16); a3[k] += __shfl_xor(a3[k], 16);
            a0[k] += __shfl_xor(a0[k], 32); a1[k] += __shfl_xor(a1[k], 32);
            a2[k] += __shfl_xor(a2[k], 32); a3[k] += __shfl_xor(a3[k], 32);
        }
        if (lane < 16) {
            float inv = idn[wid][g >> 1];
            const bf16* idp = identb + (size_t)d * 256 + f0;
            bf16x8 id0 = *(const bf16x8*)idp;
            bf16x8 id1 = *(const bf16x8*)(idp + 8);
            bf16* ob = outb + (size_t)d * 256 + f0;
            f32x4 av[4] = {a0, a1, a2, a3};
            bf16x8 obv0, obv1;
#pragma unroll
            for (int i = 0; i < 4; ++i) {
#pragma unroll
                for (int k = 0; k < 4; ++k) {
                    float v = av[i][k] * inv + loadf(bias, f0 + 4 * i + k, isf32);
                    v = (v > 0.f) ? v : (__expf(v) - 1.f);  // ELU
                    int e8 = 4 * i + k;
                    v += bf2fs((e8 < 8) ? id0[e8] : id1[e8 - 8]);
                    if (i < 2) obv0[e8] = f2bfs(v);
                    else       obv1[e8 - 8] = f2bfs(v);
                }
            }
            *(bf16x8*)ob = obv0;
            *(bf16x8*)(ob + 8) = obv1;
        }
        return;
    }

    if (mode == 2 && fast) {
        // ---- 4-edge-parallel gather: F=320, H=10 ----
        int g = lane & 15, q = lane >> 4;
        int f0 = g * 16;          // channels [f0, f0+16)
        int f1 = 256 + g * 4;     // channels [f1, f1+4)
        f32x4 a0 = {0.f,0.f,0.f,0.f}, a1 = {0.f,0.f,0.f,0.f};
        f32x4 a2 = {0.f,0.f,0.f,0.f}, a3 = {0.f,0.f,0.f,0.f};
        f32x4 a4 = {0.f,0.f,0.f,0.f};
        for (int p = q; p < deg; p += 4) {
            int s = ssrc[wid][p];
            const bf16* hp = hlin + (size_t)s * 320;
            bf16x8 h0 = *(const bf16x8*)(hp + f0);
            bf16x8 h1 = *(const bf16x8*)(hp + f0 + 8);
            bf16x4 h2 = *(const bf16x4*)(hp + f1);
            float w0 = el[wid][p * 10 + (g >> 1)];
            float w2 = el[wid][p * 10 + 8 + (g >> 3)];
#pragma unroll
            for (int k = 0; k < 4; ++k) {
                a0[k] += w0 * bf2fs(h0[k]);
                a1[k] += w0 * bf2fs(h0[4 + k]);
                a2[k] += w0 * bf2fs(h1[k]);
                a3[k] += w0 * bf2fs(h1[4 + k]);
                a4[k] += w2 * bf2fs(h2[k]);
            }
        }
#pragma unroll
        for (int k = 0; k < 4; ++k) {
            a0[k] += __shfl_xor(a0[k], 16); a1[k] += __shfl_xor(a1[k], 16);
            a2[k] += __shfl_xor(a2[k], 16); a3[k] += __shfl_xor(a3[k], 16);
            a4[k] += __shfl_xor(a4[k], 16);
            a0[k] += __shfl_xor(a0[k], 32); a1[k] += __shfl_xor(a1[k], 32);
            a2[k] += __shfl_xor(a2[k], 32); a3[k] += __shfl_xor(a3[k], 32);
            a4[k] += __shfl_xor(a4[k], 32);
        }
        float* scratch = &el[wid][0];
        if (lane < 16) {
            float inv0 = idn[wid][g >> 1];
            float inv2 = idn[wid][8 + (g >> 3)];
#pragma unroll
            for (int k = 0; k < 4; ++k) {
                scratch[f0 + k]      = a0[k] * inv0;
                scratch[f0 + 4 + k]  = a1[k] * inv0;
                scratch[f0 + 8 + k]  = a2[k] * inv0;
                scratch[f0 + 12 + k] = a3[k] * inv0;
                scratch[f1 + k]      = a4[k] * inv2;
            }
        }
        // wave-internal LDS dep; compiler inserts lgkmcnt wait
        if (lane < 32) {
            float s = 0.f;
#pragma unroll
            for (int h = 0; h < 10; ++h) s += scratch[h * 32 + lane];
            float v = s * 0.1f + loadf(bias, lane, isf32)
                    + bf2f(identb[(size_t)d * 32 + lane]);
            if (isf32) ((float*)out)[(size_t)d * 32 + lane] = v;
            else ((bf16*)out)[(size_t)d * 32 + lane] = __float2bfloat16(v);
        }
        return;
    }

    // ---- slow path (deg > CAP): recompute logits per lane-channel-group ----
    f32x4 acc[2] = {(f32x4){0.f,0.f,0.f,0.f}, (f32x4){0.f,0.f,0.f,0.f}};
    for (int j = 0; j < nj; ++j) {
        int f0 = (lane + 64 * j) * 4;
        if (f0 >= F) continue;
        int hj = f0 >> 5;
        float ad = adst[(size_t)d * H + hj];
        float m = -1e30f;
        for (int p = 0; p < deg; ++p) {
            int e = csr_e[lo + p];
            int s = (e < E) ? esrc[e] : (e - E);
            float v = asrc[(size_t)s * H + hj] + ad;
            v = (v > 0.f) ? v : 0.2f * v;
            m = fmaxf(m, v);
        }
        float den = 0.f;
        f32x4 a4 = {0.f, 0.f, 0.f, 0.f};
        for (int p = 0; p < deg; ++p) {
            int e = csr_e[lo + p];
            int s = (e < E) ? esrc[e] : (e - E);
            float v = asrc[(size_t)s * H + hj] + ad;
            v = (v > 0.f) ? v : 0.2f * v;
            float t = __expf(v - m);
            den += t;
            bf16x4 hv = *(const bf16x4*)(hlin + (size_t)s * F + f0);
            for (int k = 0; k < 4; ++k) a4[k] += t * bf2fs(hv[k]);
        }
        float inv = 1.f / (den + 1e-16f);
        for (int k = 0; k < 4; ++k) acc[j][k] = a4[k] * inv;
    }
    // slow-path epilogues
    if (mode == 1) {
        int f0 = lane * 4;
        bf16x4 ob;
#pragma unroll
        for (int k = 0; k < 4; ++k) {
            float v = acc[0][k] + loadf(bias, f0 + k, isf32);
            v = (v > 0.f) ? v : (__expf(v) - 1.f);
            v += bf2f(identb[(size_t)d * F + f0 + k]);
            ob[k] = f2bfs(v);
        }
        *(bf16x4*)(outb + (size_t)d * F + f0) = ob;
    } else {
        float* scratch = &el[wid][0];
#pragma unroll
        for (int j = 0; j < 2; ++j) {
            int f0 = (lane + 64 * j) * 4;
            if (j < nj && f0 < F) {
#pragma unroll
                for (int k = 0; k < 4; ++k) scratch[f0 + k] = acc[j][k];
            }
        }
        if (lane < 32) {
            float s = 0.f;
            for (int h = 0; h < H; ++h) s += scratch[h * 32 + lane];
            float v = s * (1.f / (float)H) + loadf(bias, lane, isf32)
                    + bf2f(identb[(size_t)d * 32 + lane]);
            if (isf32) ((float*)out)[(size_t)d * 32 + lane] = v;
            else ((bf16*)out)[(size_t)d * 32 + lane] = __float2bfloat16(v);
        }
    }
}

extern "C" void kernel_launch(void* const* d_in, const int* in_sizes, int n_in,
                              void* d_out, int out_size, void* d_ws, size_t ws_size,
                              hipStream_t stream) {
    const int IN = 256, C = 32;
    const int N = in_sizes[0] / IN;
    const int E = in_sizes[1] / 2;
    const int ET = E + N;

    const void* x    = d_in[0];
    const int*  edge = (const int*)d_in[1];
    const void* W1 = d_in[2];
    const void* a1s = d_in[3];
    const void* a1d = d_in[4];
    const void* b1 = d_in[5];
    const void* W2 = d_in[6];
    const void* a2s = d_in[7];
    const void* a2d = d_in[8];
    const void* b2 = d_in[9];
    const void* W3 = d_in[10];
    const void* a3s = d_in[11];
    const void* a3d = d_in[12];
    const void* b3 = d_in[13];
    const void* P1W = d_in[14];
    const void* P1b = d_in[15];
    const void* P3W = d_in[16];
    const void* P3b = d_in[17];

    char* ws = (char*)d_ws;
    size_t off = 0;
    auto alloc = [&](size_t bytes) -> void* {
        void* p = ws + off;
        off = (off + bytes + 255) & ~(size_t)255;
        return p;
    };
    bf16* fxb   = (bf16*)alloc((size_t)N * 256 * 2);    // bf16 input
    bf16* fyb   = (bf16*)alloc((size_t)N * 256 * 2);    // bf16 layer outputs
    bf16* fhb   = (bf16*)alloc((size_t)N * 320 * 2);    // h_lin bf16 (per layer)
    bf16* fidb  = (bf16*)alloc((size_t)N * 256 * 2);    // identity1 / identity3 (bf16)
    float* fasrc = (float*)alloc((size_t)N * 10 * 4);
    float* fadst = (float*)alloc((size_t)N * 10 * 4);
    bf16* wc1   = (bf16*)alloc((size_t)512 * 256 * 2);  // [W1; P1W]
    bf16* wb2   = (bf16*)alloc((size_t)256 * 256 * 2);
    bf16* wc3   = (bf16*)alloc((size_t)384 * 256 * 2);  // [W3; P3W; 32 pad rows]
    int*  isrc  = (int*)alloc((size_t)E * 4);
    int*  idst  = (int*)alloc((size_t)E * 4);
    int*  irow  = (int*)alloc((size_t)(N + 1) * 4);
    int*  icur  = (int*)alloc((size_t)N * 4);
    int*  icsr  = (int*)alloc((size_t)ET * 4);
    int*  flags = (int*)alloc(4 * 4);
    (void)ws_size;

    auto cdiv = [](int a, int b) { return (a + b - 1) / b; };

    // zero flags + degree counters (no graph-captured memset nodes)
    k_zero<<<cdiv(N, 256), 256, 0, stream>>>(flags, icur, N);

    // dtype detection (tiny prefix probe, block-aggregated)
    int nprobe_x = (N * 256 < 16384) ? N * 256 : 16384;
    int nprobe_e = (2 * E < 8192) ? 2 * E : 8192;
    int bx = cdiv(nprobe_x, 256) < 16 ? cdiv(nprobe_x, 256) : 16;
    int be = cdiv(nprobe_e, 256) < 8 ? cdiv(nprobe_e, 256) : 8;
    k_detect<<<bx + be, 256, 0, stream>>>(
        (const unsigned short*)x, edge, flags, nprobe_x, nprobe_e, bx);

    // normalize inputs (single fused cast launch; counts in 8-elem units)
    int c_x = N * 256 / 8, c_w = 256 * 256 / 8, c_w3 = 320 * 256 / 8, c_p3 = 32 * 256 / 8;
    int ctot = c_x + 3 * c_w + c_w3 + c_p3;
    k_cast_all<<<cdiv(ctot, 256), 256, 0, stream>>>(
        x, fxb, c_x,
        W1, wc1, c_w,
        P1W, wc1 + (size_t)256 * 256, c_w,
        W2, wb2, c_w,
        W3, wc3, c_w3,
        P3W, wc3 + (size_t)320 * 256, c_p3,
        flags);

    // CSR over dst (edges + self-loops)
    k_norm_count<<<cdiv(E, 256), 256, 0, stream>>>(edge, flags, isrc, idst, icur, E);
    k_scan<<<1, 1024, 0, stream>>>(icur, irow, N);
    k_fill<<<cdiv(ET, 256), 256, 0, stream>>>(idst, icur, irow, icsr, E, N);

    int gx = cdiv(N, 64);
    int ga = cdiv(N, 4);

    // ---- Layer 1: H=8; combined [W1;P1W] GEMM + fused alpha ----
    {
        int H = 8;
        k_gemm_split<4><<<dim3(gx, 8), 256, 0, stream>>>(
            fxb, wc1, P1b, flags, fhb, 256, 256, fidb, 256, 256, N, 512, 256,
            a1s, a1d, fasrc, fadst, H);
        k_fused_agg<<<ga, 256, 0, stream>>>(fhb, fasrc, fadst, isrc, irow, icsr,
                                            b1, fidb, nullptr, fyb, flags, E, N, H, 1);
    }
    // ---- Layer 2: H=8, identity = layer-1 output (bf16, in-place) ----
    {
        int H = 8;
        k_gemm_split<4><<<dim3(gx, 4), 256, 0, stream>>>(
            fyb, wb2, nullptr, flags, fhb, 256, 256, nullptr, 0, 0, N, 256, 256,
            a2s, a2d, fasrc, fadst, H);
        k_fused_agg<<<ga, 256, 0, stream>>>(fhb, fasrc, fadst, isrc, irow, icsr,
                                            b2, fyb, nullptr, fyb, flags, E, N, H, 1);
    }
    // ---- Layer 3: H=10, concat=False; combined [W3;P3W;pad] GEMM ----
    {
        int H = 10;
        k_gemm_split<4><<<dim3(gx, 6), 256, 0, stream>>>(
            fyb, wc3, P3b, flags, fhb, 320, 320, fidb, 32, 32, N, 384, 256,
            a3s, a3d, fasrc, fadst, H);
        k_fused_agg<<<ga, 256, 0, stream>>>(fhb, fasrc, fadst, isrc, irow, icsr,
                                            b3, fidb, d_out, nullptr, flags, E, N, H, 2);
    }
}